// Round 7
// baseline (514.583 us; speedup 1.0000x reference)
//
#include <hip/hip_runtime.h>
#include <math.h>

constexpr int Bc = 4, Tc = 1024, Ec = 1024, Hc = 16, Fc = 64;

typedef __attribute__((ext_vector_type(8))) short bf16x8;
typedef __attribute__((ext_vector_type(4))) float f32x4;

__device__ __forceinline__ ushort f2bf(float x) {
  union { float f; unsigned u; } v; v.f = x;
  unsigned r = v.u + 0x7fffu + ((v.u >> 16) & 1u);
  return (ushort)(r >> 16);
}
__device__ __forceinline__ float bf2f(ushort h) {
  union { float f; unsigned u; } v; v.u = ((unsigned)h) << 16; return v.f;
}
__device__ __forceinline__ void split3(float x, ushort& h, ushort& m, ushort& l) {
  h = f2bf(x);
  float r1 = x - bf2f(h);
  m = f2bf(r1);
  float r2 = r1 - bf2f(m);
  l = f2bf(r2);
}
__device__ __forceinline__ void split2(float x, ushort& h, ushort& l) {
  h = f2bf(x);
  l = f2bf(x - bf2f(h));
}

// ---------------------------------------------------------------------------
// Pre-transpose + split projection weights (unchanged).
// ---------------------------------------------------------------------------
__global__ __launch_bounds__(256) void transp_w(
    const float* __restrict__ qw, const float* __restrict__ kw,
    const float* __restrict__ vw, ushort* __restrict__ wT)
{
  const int zi = blockIdx.z;
  const float* src = (zi == 0) ? qw : (zi == 1) ? kw : vw;
  ushort* dst = wT + (size_t)(zi * 3) * (1u << 20);
  const int ns = (zi == 2) ? 1 : 3;
  const int h = blockIdx.y, e0 = blockIdx.x * 64;
  __shared__ float T[64][68];
  const int tid = threadIdx.x;
  {
    const int er = tid >> 4, fr = (tid & 15) * 4;
#pragma unroll
    for (int i = 0; i < 4; ++i) {
      const float4 v = *(const float4*)&src[((size_t)(h * 1024 + e0 + er + i * 16)) * 64 + fr];
      *(float4*)&T[er + i * 16][fr] = v;
    }
  }
  __syncthreads();
  const int f = tid >> 2, eo = (tid & 3) * 16;
  ushort hs[16], ms[16], ls[16];
#pragma unroll
  for (int j = 0; j < 16; ++j) {
    split3(T[eo + j][f], hs[j], ms[j], ls[j]);
  }
  const size_t nbase = (size_t)(h * 64 + f) * 1024 + e0 + eo;
  bf16x8 v0, v1;
#pragma unroll
  for (int j = 0; j < 8; ++j) { v0[j] = (short)hs[j]; v1[j] = (short)hs[j + 8]; }
  *(bf16x8*)&dst[nbase] = v0; *(bf16x8*)&dst[nbase + 8] = v1;
  if (ns == 3) {
#pragma unroll
    for (int j = 0; j < 8; ++j) { v0[j] = (short)ms[j]; v1[j] = (short)ms[j + 8]; }
    *(bf16x8*)&dst[(1u << 20) + nbase] = v0; *(bf16x8*)&dst[(1u << 20) + nbase + 8] = v1;
#pragma unroll
    for (int j = 0; j < 8; ++j) { v0[j] = (short)ls[j]; v1[j] = (short)ls[j + 8]; }
    *(bf16x8*)&dst[(2u << 20) + nbase] = v0; *(bf16x8*)&dst[(2u << 20) + nbase + 8] = v1;
  }
}

// ---------------------------------------------------------------------------
// Pre-transpose + split2 fr weights (unchanged).
// ---------------------------------------------------------------------------
__global__ __launch_bounds__(256) void transp_frw(
    const float* __restrict__ frw, ushort* __restrict__ frT)
{
  const int bb = blockIdx.z;
  const int e0 = blockIdx.x * 64, d0 = blockIdx.y * 64;
  __shared__ float T[64][68];
  const int tid = threadIdx.x;
  {
    const int er = tid >> 4, dr = (tid & 15) * 4;
#pragma unroll
    for (int i = 0; i < 4; ++i) {
      const float4 v = *(const float4*)&frw[((size_t)bb * 1024 + e0 + er + i * 16) * 1024 + d0 + dr];
      *(float4*)&T[er + i * 16][dr] = v;
    }
  }
  __syncthreads();
  const int d = tid >> 2, eo = (tid & 3) * 16;
  ushort hs[16], ls[16];
#pragma unroll
  for (int j = 0; j < 16; ++j) split2(T[eo + j][d], hs[j], ls[j]);
  const size_t nbase = ((size_t)bb * 1024 + d0 + d) * 1024 + e0 + eo;
  bf16x8 v0, v1;
#pragma unroll
  for (int j = 0; j < 8; ++j) { v0[j] = (short)hs[j]; v1[j] = (short)hs[j + 8]; }
  *(bf16x8*)&frT[nbase] = v0; *(bf16x8*)&frT[nbase + 8] = v1;
#pragma unroll
  for (int j = 0; j < 8; ++j) { v0[j] = (short)ls[j]; v1[j] = (short)ls[j + 8]; }
  *(bf16x8*)&frT[(4u << 20) + nbase] = v0; *(bf16x8*)&frT[(4u << 20) + nbase + 8] = v1;
}

// ---------------------------------------------------------------------------
// q/k projection MFMA. q written fp32 [bh][t][f]; k written PRE-SPLIT bf16
// kh/km/kl [bh][t][f] (moves the K split3 out of attn's hot loop).
// ---------------------------------------------------------------------------
__global__ __launch_bounds__(256) void proj_qk_mfma(
    const float* __restrict__ x, const ushort* __restrict__ wT,
    float* __restrict__ qf, ushort* __restrict__ kh,
    ushort* __restrict__ km, ushort* __restrict__ kl)
{
  const int zi = blockIdx.z;
  const ushort* wt = wT + (size_t)zi * 3 * (1u << 20);
  const int m0 = blockIdx.x * 128, n0 = blockIdx.y * 128;
  __shared__ ushort As[3][128][36];
  __shared__ ushort Bs[3][128][36];
  const int tid = threadIdx.x;
  const int wave = tid >> 6, lane = tid & 63, l15 = lane & 15, quad = lane >> 4;
  const int wm = wave >> 1, wn = wave & 1;
  const int sr = tid >> 1, sk = (tid & 1) * 16;
  f32x4 acc[4][4] = {};
  for (int k0 = 0; k0 < 1024; k0 += 32) {
    __syncthreads();
    {
      const float* ap = x + (size_t)(m0 + sr) * 1024 + k0 + sk;
      float xs[16];
      *(float4*)&xs[0]  = *(const float4*)(ap);
      *(float4*)&xs[4]  = *(const float4*)(ap + 4);
      *(float4*)&xs[8]  = *(const float4*)(ap + 8);
      *(float4*)&xs[12] = *(const float4*)(ap + 12);
      bf16x8 h0, h1, m0v, m1v, l0, l1;
#pragma unroll
      for (int j = 0; j < 8; ++j) {
        ushort hu, mu, lu;
        split3(xs[j], hu, mu, lu);
        h0[j] = (short)hu; m0v[j] = (short)mu; l0[j] = (short)lu;
        split3(xs[j + 8], hu, mu, lu);
        h1[j] = (short)hu; m1v[j] = (short)mu; l1[j] = (short)lu;
      }
      *(bf16x8*)&As[0][sr][sk] = h0;  *(bf16x8*)&As[0][sr][sk + 8] = h1;
      *(bf16x8*)&As[1][sr][sk] = m0v; *(bf16x8*)&As[1][sr][sk + 8] = m1v;
      *(bf16x8*)&As[2][sr][sk] = l0;  *(bf16x8*)&As[2][sr][sk + 8] = l1;
#pragma unroll
      for (int s = 0; s < 3; ++s) {
        const ushort* bp = wt + ((size_t)s << 20) + (size_t)(n0 + sr) * 1024 + k0 + sk;
        *(bf16x8*)&Bs[s][sr][sk]     = *(const bf16x8*)(bp);
        *(bf16x8*)&Bs[s][sr][sk + 8] = *(const bf16x8*)(bp + 8);
      }
    }
    __syncthreads();
    bf16x8 af[4][3];
#pragma unroll
    for (int tm = 0; tm < 4; ++tm)
#pragma unroll
      for (int s = 0; s < 3; ++s)
        af[tm][s] = *(const bf16x8*)&As[s][wm * 64 + tm * 16 + l15][quad * 8];
#pragma unroll
    for (int tn = 0; tn < 4; ++tn) {
      const int nrow = wn * 64 + tn * 16 + l15;
      bf16x8 b0 = *(const bf16x8*)&Bs[0][nrow][quad * 8];
      bf16x8 b1 = *(const bf16x8*)&Bs[1][nrow][quad * 8];
      bf16x8 b2 = *(const bf16x8*)&Bs[2][nrow][quad * 8];
#pragma unroll
      for (int tm = 0; tm < 4; ++tm) {
        f32x4 a = acc[tm][tn];
        a = __builtin_amdgcn_mfma_f32_16x16x32_bf16(af[tm][0], b0, a, 0, 0, 0);
        a = __builtin_amdgcn_mfma_f32_16x16x32_bf16(af[tm][0], b1, a, 0, 0, 0);
        a = __builtin_amdgcn_mfma_f32_16x16x32_bf16(af[tm][1], b0, a, 0, 0, 0);
        a = __builtin_amdgcn_mfma_f32_16x16x32_bf16(af[tm][0], b2, a, 0, 0, 0);
        a = __builtin_amdgcn_mfma_f32_16x16x32_bf16(af[tm][1], b1, a, 0, 0, 0);
        a = __builtin_amdgcn_mfma_f32_16x16x32_bf16(af[tm][2], b0, a, 0, 0, 0);
        acc[tm][tn] = a;
      }
    }
  }
#pragma unroll
  for (int tm = 0; tm < 4; ++tm) {
#pragma unroll
    for (int tn = 0; tn < 4; ++tn) {
#pragma unroll
      for (int r = 0; r < 4; ++r) {
        int m = m0 + wm * 64 + tm * 16 + quad * 4 + r;
        int n = n0 + wn * 64 + tn * 16 + l15;
        int b = m >> 10, t = m & 1023, h = n >> 6, f = n & 63;
        size_t idx = (((size_t)(b * 16 + h)) * 1024 + t) * 64 + f;
        if (zi == 0) {
          qf[idx] = acc[tm][tn][r];
        } else {
          ushort hu, mu, lu;
          split3(acc[tm][tn][r], hu, mu, lu);
          kh[idx] = hu; km[idx] = mu; kl[idx] = lu;
        }
      }
    }
  }
}

// ---------------------------------------------------------------------------
// v projection MFMA (unchanged).
// ---------------------------------------------------------------------------
__global__ __launch_bounds__(256) void proj_v_mfma(
    const float* __restrict__ x, const ushort* __restrict__ wT,
    ushort* __restrict__ vt)
{
  const ushort* wt = wT + (size_t)6 * (1u << 20);
  const int m0 = blockIdx.x * 128, n0 = blockIdx.y * 128;
  __shared__ ushort As[128][36];
  __shared__ ushort Bs[128][36];
  const int tid = threadIdx.x;
  const int wave = tid >> 6, lane = tid & 63, l15 = lane & 15, quad = lane >> 4;
  const int wm = wave >> 1, wn = wave & 1;
  const int sr = tid >> 1, sk = (tid & 1) * 16;
  f32x4 acc[4][4] = {};
  for (int k0 = 0; k0 < 1024; k0 += 32) {
    __syncthreads();
    {
      const float* ap = x + (size_t)(m0 + sr) * 1024 + k0 + sk;
      float xs[16];
      *(float4*)&xs[0]  = *(const float4*)(ap);
      *(float4*)&xs[4]  = *(const float4*)(ap + 4);
      *(float4*)&xs[8]  = *(const float4*)(ap + 8);
      *(float4*)&xs[12] = *(const float4*)(ap + 12);
      bf16x8 h0, h1;
#pragma unroll
      for (int j = 0; j < 8; ++j) {
        h0[j] = (short)f2bf(xs[j]);
        h1[j] = (short)f2bf(xs[j + 8]);
      }
      *(bf16x8*)&As[sr][sk] = h0; *(bf16x8*)&As[sr][sk + 8] = h1;
      const ushort* bp = wt + (size_t)(n0 + sr) * 1024 + k0 + sk;
      *(bf16x8*)&Bs[sr][sk]     = *(const bf16x8*)(bp);
      *(bf16x8*)&Bs[sr][sk + 8] = *(const bf16x8*)(bp + 8);
    }
    __syncthreads();
    bf16x8 af[4];
#pragma unroll
    for (int tm = 0; tm < 4; ++tm)
      af[tm] = *(const bf16x8*)&As[wm * 64 + tm * 16 + l15][quad * 8];
#pragma unroll
    for (int tn = 0; tn < 4; ++tn) {
      bf16x8 b0 = *(const bf16x8*)&Bs[wn * 64 + tn * 16 + l15][quad * 8];
#pragma unroll
      for (int tm = 0; tm < 4; ++tm)
        acc[tm][tn] = __builtin_amdgcn_mfma_f32_16x16x32_bf16(af[tm], b0, acc[tm][tn], 0, 0, 0);
    }
  }
#pragma unroll
  for (int tm = 0; tm < 4; ++tm) {
#pragma unroll
    for (int tn = 0; tn < 4; ++tn) {
#pragma unroll
      for (int r = 0; r < 4; ++r) {
        int m = m0 + wm * 64 + tm * 16 + quad * 4 + r;
        int n = n0 + wn * 64 + tn * 16 + l15;
        int b = m >> 10, t = m & 1023, h = n >> 6, f = n & 63;
        vt[(((size_t)(b * 16 + h)) * 64 + f) * 1024 + t] = f2bf(acc[tm][tn][r]);
      }
    }
  }
}

// ---------------------------------------------------------------------------
// Flash attention. K pre-split (pure copy staging, no split3 in loop).
// LDS pad 68 (34 dwords): staging b128 writes 2-way (free) vs 8-way at 72.
// ---------------------------------------------------------------------------
__global__ __launch_bounds__(256) void attn_mfma(
    const float* __restrict__ qf, const ushort* __restrict__ kh,
    const ushort* __restrict__ km, const ushort* __restrict__ kl,
    const ushort* __restrict__ vt, float* __restrict__ z)
{
  __shared__ ushort Ks[3][64][68];
  __shared__ ushort Vs[64][68];
  __shared__ ushort Pl[4][16][68];

  const int tid = threadIdx.x;
  const int wave = tid >> 6, lane = tid & 63;
  const int l15 = lane & 15, quad = lane >> 4;
  const int bh = blockIdx.y;
  const int qbase = blockIdx.x * 64;

  bf16x8 aqh[2], aqm[2], aql[2];
  {
    const int qrow = qbase + wave * 16 + l15;
    const float* qp = qf + ((size_t)bh * Tc + qrow) * Fc;
#pragma unroll
    for (int ks = 0; ks < 2; ++ks) {
      int f0 = ks * 32 + quad * 8;
      float4 x0 = *(const float4*)(qp + f0);
      float4 x1 = *(const float4*)(qp + f0 + 4);
      float xs[8] = {x0.x, x0.y, x0.z, x0.w, x1.x, x1.y, x1.z, x1.w};
#pragma unroll
      for (int j = 0; j < 8; ++j) {
        ushort hu, mu, lu;
        split3(xs[j], hu, mu, lu);
        aqh[ks][j] = (short)hu; aqm[ks][j] = (short)mu; aql[ks][j] = (short)lu;
      }
    }
  }

  f32x4 o[4] = {{0,0,0,0},{0,0,0,0},{0,0,0,0},{0,0,0,0}};
  float m_run[4], l_run[4];
#pragma unroll
  for (int r = 0; r < 4; ++r) { m_run[r] = -1e30f; l_run[r] = 0.f; }

  const int srow = tid >> 2, sc = tid & 3;
  const size_t kbase = (size_t)bh * Tc * Fc;   // ushort offset
  const size_t vbase = (size_t)bh * Fc * Tc;
  const ushort* kp0 = kh + kbase + (size_t)srow * Fc + sc * 16;
  const ushort* kp1 = km + kbase + (size_t)srow * Fc + sc * 16;
  const ushort* kp2 = kl + kbase + (size_t)srow * Fc + sc * 16;
  const ushort* vp  = vt + vbase + (size_t)srow * Tc + sc * 16;

  for (int kt = 0; kt < Tc; kt += 64) {
    __syncthreads();
    {
      const size_t ko = (size_t)kt * Fc;
      *(bf16x8*)&Ks[0][srow][sc * 16]     = *(const bf16x8*)(kp0 + ko);
      *(bf16x8*)&Ks[0][srow][sc * 16 + 8] = *(const bf16x8*)(kp0 + ko + 8);
      *(bf16x8*)&Ks[1][srow][sc * 16]     = *(const bf16x8*)(kp1 + ko);
      *(bf16x8*)&Ks[1][srow][sc * 16 + 8] = *(const bf16x8*)(kp1 + ko + 8);
      *(bf16x8*)&Ks[2][srow][sc * 16]     = *(const bf16x8*)(kp2 + ko);
      *(bf16x8*)&Ks[2][srow][sc * 16 + 8] = *(const bf16x8*)(kp2 + ko + 8);
      *(bf16x8*)&Vs[srow][sc * 16]        = *(const bf16x8*)(vp + kt);
      *(bf16x8*)&Vs[srow][sc * 16 + 8]    = *(const bf16x8*)(vp + kt + 8);
    }
    __syncthreads();

    f32x4 sacc[4] = {{0,0,0,0},{0,0,0,0},{0,0,0,0},{0,0,0,0}};
#pragma unroll
    for (int nt = 0; nt < 4; ++nt) {
      int key = nt * 16 + l15;
#pragma unroll
      for (int ks = 0; ks < 2; ++ks) {
        int f0 = ks * 32 + quad * 8;
        bf16x8 bh_ = *(const bf16x8*)&Ks[0][key][f0];
        bf16x8 bm_ = *(const bf16x8*)&Ks[1][key][f0];
        bf16x8 bl_ = *(const bf16x8*)&Ks[2][key][f0];
        sacc[nt] = __builtin_amdgcn_mfma_f32_16x16x32_bf16(aqh[ks], bh_, sacc[nt], 0, 0, 0);
        sacc[nt] = __builtin_amdgcn_mfma_f32_16x16x32_bf16(aqh[ks], bm_, sacc[nt], 0, 0, 0);
        sacc[nt] = __builtin_amdgcn_mfma_f32_16x16x32_bf16(aqm[ks], bh_, sacc[nt], 0, 0, 0);
        sacc[nt] = __builtin_amdgcn_mfma_f32_16x16x32_bf16(aqh[ks], bl_, sacc[nt], 0, 0, 0);
        sacc[nt] = __builtin_amdgcn_mfma_f32_16x16x32_bf16(aqm[ks], bm_, sacc[nt], 0, 0, 0);
        sacc[nt] = __builtin_amdgcn_mfma_f32_16x16x32_bf16(aql[ks], bh_, sacc[nt], 0, 0, 0);
      }
    }

    const int rowg0 = qbase + wave * 16 + quad * 4;
    float mx[4];
#pragma unroll
    for (int r = 0; r < 4; ++r) mx[r] = -1e30f;
#pragma unroll
    for (int nt = 0; nt < 4; ++nt) {
      int key = kt + nt * 16 + l15;
#pragma unroll
      for (int r = 0; r < 4; ++r) {
        float s = sacc[nt][r];
        if (key > rowg0 + r) s *= -1.0e9f + 1.0f;
        s *= 0.125f;
        sacc[nt][r] = s;
        mx[r] = fmaxf(mx[r], s);
      }
    }
#pragma unroll
    for (int r = 0; r < 4; ++r)
#pragma unroll
      for (int d = 1; d < 16; d <<= 1) mx[r] = fmaxf(mx[r], __shfl_xor(mx[r], d));

    float corr[4], ps[4];
#pragma unroll
    for (int r = 0; r < 4; ++r) {
      float m2 = fmaxf(m_run[r], mx[r]);
      corr[r] = __expf(m_run[r] - m2);
      m_run[r] = m2;
      ps[r] = 0.f;
    }
#pragma unroll
    for (int nt = 0; nt < 4; ++nt) {
#pragma unroll
      for (int r = 0; r < 4; ++r) {
        float p = __expf(sacc[nt][r] - m_run[r]);
        ps[r] += p;
        Pl[wave][quad * 4 + r][nt * 16 + l15] = f2bf(p);
      }
    }
#pragma unroll
    for (int r = 0; r < 4; ++r) {
#pragma unroll
      for (int d = 1; d < 16; d <<= 1) ps[r] += __shfl_xor(ps[r], d);
      l_run[r] = l_run[r] * corr[r] + ps[r];
#pragma unroll
      for (int ft = 0; ft < 4; ++ft) o[ft][r] *= corr[r];
    }

#pragma unroll
    for (int ks2 = 0; ks2 < 2; ++ks2) {
      bf16x8 pa = *(const bf16x8*)&Pl[wave][l15][ks2 * 32 + quad * 8];
#pragma unroll
      for (int ft = 0; ft < 4; ++ft) {
        bf16x8 vb = *(const bf16x8*)&Vs[ft * 16 + l15][ks2 * 32 + quad * 8];
        o[ft] = __builtin_amdgcn_mfma_f32_16x16x32_bf16(pa, vb, o[ft], 0, 0, 0);
      }
    }
  }

  const int b = bh >> 4, h = bh & 15;
#pragma unroll
  for (int r = 0; r < 4; ++r) {
    float inv = 1.f / l_run[r];
    int row = qbase + wave * 16 + quad * 4 + r;
    float* zp = z + ((size_t)(b * Tc + row)) * Ec + h * Fc;
#pragma unroll
    for (int ft = 0; ft < 4; ++ft) zp[ft * 16 + l15] = o[ft][r] * inv;
  }
}

// ---------------------------------------------------------------------------
// fr GEMM, split2 MFMA (unchanged).
// ---------------------------------------------------------------------------
__global__ __launch_bounds__(256) void gemm_fr_mfma(
    const float* __restrict__ z, const ushort* __restrict__ frT,
    const float* __restrict__ x, float* __restrict__ s1,
    float2* __restrict__ part)
{
  const int bb = blockIdx.z;
  const int m0 = blockIdx.x * 128, n0 = blockIdx.y * 128;
  __shared__ ushort Ah[128][36], Al[128][36];
  __shared__ ushort Bh[128][36], Bl[128][36];
  __shared__ float2 red[256];
  const int tid = threadIdx.x;
  const int wave = tid >> 6, lane = tid & 63, l15 = lane & 15, quad = lane >> 4;
  const int wm = wave >> 1, wn = wave & 1;
  const int sr = tid >> 1, sk = (tid & 1) * 16;
  f32x4 acc[4][4] = {};
  const ushort* bhp = frT + ((size_t)bb * 1024 + n0) * 1024;
  const ushort* blp = bhp + (4u << 20);
  for (int k0 = 0; k0 < 1024; k0 += 32) {
    __syncthreads();
    {
      const float* ap = z + ((size_t)bb * 1024 + m0 + sr) * 1024 + k0 + sk;
      float xs[16];
      *(float4*)&xs[0]  = *(const float4*)(ap);
      *(float4*)&xs[4]  = *(const float4*)(ap + 4);
      *(float4*)&xs[8]  = *(const float4*)(ap + 8);
      *(float4*)&xs[12] = *(const float4*)(ap + 12);
      bf16x8 h0, h1, l0, l1;
#pragma unroll
      for (int j = 0; j < 8; ++j) {
        ushort hu, lu;
        split2(xs[j], hu, lu);     h0[j] = (short)hu; l0[j] = (short)lu;
        split2(xs[j + 8], hu, lu); h1[j] = (short)hu; l1[j] = (short)lu;
      }
      *(bf16x8*)&Ah[sr][sk] = h0; *(bf16x8*)&Ah[sr][sk + 8] = h1;
      *(bf16x8*)&Al[sr][sk] = l0; *(bf16x8*)&Al[sr][sk + 8] = l1;
      const size_t boff = (size_t)sr * 1024 + k0 + sk;
      *(bf16x8*)&Bh[sr][sk]     = *(const bf16x8*)(bhp + boff);
      *(bf16x8*)&Bh[sr][sk + 8] = *(const bf16x8*)(bhp + boff + 8);
      *(bf16x8*)&Bl[sr][sk]     = *(const bf16x8*)(blp + boff);
      *(bf16x8*)&Bl[sr][sk + 8] = *(const bf16x8*)(blp + boff + 8);
    }
    __syncthreads();
    bf16x8 ah[4], al[4];
#pragma unroll
    for (int tm = 0; tm < 4; ++tm) {
      ah[tm] = *(const bf16x8*)&Ah[wm * 64 + tm * 16 + l15][quad * 8];
      al[tm] = *(const bf16x8*)&Al[wm * 64 + tm * 16 + l15][quad * 8];
    }
#pragma unroll
    for (int tn = 0; tn < 4; ++tn) {
      const int nrow = wn * 64 + tn * 16 + l15;
      bf16x8 b0 = *(const bf16x8*)&Bh[nrow][quad * 8];
      bf16x8 b1 = *(const bf16x8*)&Bl[nrow][quad * 8];
#pragma unroll
      for (int tm = 0; tm < 4; ++tm) {
        f32x4 a = acc[tm][tn];
        a = __builtin_amdgcn_mfma_f32_16x16x32_bf16(ah[tm], b0, a, 0, 0, 0);
        a = __builtin_amdgcn_mfma_f32_16x16x32_bf16(ah[tm], b1, a, 0, 0, 0);
        a = __builtin_amdgcn_mfma_f32_16x16x32_bf16(al[tm], b0, a, 0, 0, 0);
        acc[tm][tn] = a;
      }
    }
  }
  float sum = 0.f, sq = 0.f;
#pragma unroll
  for (int tm = 0; tm < 4; ++tm) {
#pragma unroll
    for (int tn = 0; tn < 4; ++tn) {
#pragma unroll
      for (int r = 0; r < 4; ++r) {
        int m = m0 + wm * 64 + tm * 16 + quad * 4 + r;
        int n = n0 + wn * 64 + tn * 16 + l15;
        size_t idx = ((size_t)bb * 1024 + m) * 1024 + n;
        float o = x[idx] + acc[tm][tn][r];
        s1[idx] = o;
        sum += o; sq += o * o;
      }
    }
  }
  red[tid] = make_float2(sum, sq);
  __syncthreads();
  for (int s = 128; s > 0; s >>= 1) {
    if (tid < s) { red[tid].x += red[tid + s].x; red[tid].y += red[tid + s].y; }
    __syncthreads();
  }
  if (tid == 0) part[(bb * 8 + blockIdx.x) * 8 + blockIdx.y] = red[0];
}

// ---------------------------------------------------------------------------
// ff GEMM, split2 MFMA (unchanged).
// ---------------------------------------------------------------------------
__global__ __launch_bounds__(256) void gemm_ff_mfma(
    const float* __restrict__ z1, const float* __restrict__ ffw,
    const float* __restrict__ ffb, float* __restrict__ s2,
    float2* __restrict__ part)
{
  const int m0 = blockIdx.x * 128, n0 = blockIdx.y * 128;
  __shared__ ushort Ah[128][36], Al[128][36];
  __shared__ ushort Bh[128][36], Bl[128][36];
  __shared__ float2 red[256];
  const int tid = threadIdx.x;
  const int wave = tid >> 6, lane = tid & 63, l15 = lane & 15, quad = lane >> 4;
  const int wm = wave >> 1, wn = wave & 1;
  const int sr = tid >> 1, sk = (tid & 1) * 16;
  f32x4 acc[4][4] = {};
  for (int k0 = 0; k0 < 1024; k0 += 32) {
    __syncthreads();
    {
      const float* ap = z1 + (size_t)(m0 + sr) * 1024 + k0 + sk;
      const float* bp = ffw + (size_t)(n0 + sr) * 1024 + k0 + sk;
      float xs[16], ys[16];
      *(float4*)&xs[0]  = *(const float4*)(ap);
      *(float4*)&xs[4]  = *(const float4*)(ap + 4);
      *(float4*)&xs[8]  = *(const float4*)(ap + 8);
      *(float4*)&xs[12] = *(const float4*)(ap + 12);
      *(float4*)&ys[0]  = *(const float4*)(bp);
      *(float4*)&ys[4]  = *(const float4*)(bp + 4);
      *(float4*)&ys[8]  = *(const float4*)(bp + 8);
      *(float4*)&ys[12] = *(const float4*)(bp + 12);
      bf16x8 h0, h1, l0, l1, g0, g1, e0, e1;
#pragma unroll
      for (int j = 0; j < 8; ++j) {
        ushort hu, lu;
        split2(xs[j], hu, lu);     h0[j] = (short)hu; l0[j] = (short)lu;
        split2(xs[j + 8], hu, lu); h1[j] = (short)hu; l1[j] = (short)lu;
        split2(ys[j], hu, lu);     g0[j] = (short)hu; e0[j] = (short)lu;
        split2(ys[j + 8], hu, lu); g1[j] = (short)hu; e1[j] = (short)lu;
      }
      *(bf16x8*)&Ah[sr][sk] = h0; *(bf16x8*)&Ah[sr][sk + 8] = h1;
      *(bf16x8*)&Al[sr][sk] = l0; *(bf16x8*)&Al[sr][sk + 8] = l1;
      *(bf16x8*)&Bh[sr][sk] = g0; *(bf16x8*)&Bh[sr][sk + 8] = g1;
      *(bf16x8*)&Bl[sr][sk] = e0; *(bf16x8*)&Bl[sr][sk + 8] = e1;
    }
    __syncthreads();
    bf16x8 ah[4], al[4];
#pragma unroll
    for (int tm = 0; tm < 4; ++tm) {
      ah[tm] = *(const bf16x8*)&Ah[wm * 64 + tm * 16 + l15][quad * 8];
      al[tm] = *(const bf16x8*)&Al[wm * 64 + tm * 16 + l15][quad * 8];
    }
#pragma unroll
    for (int tn = 0; tn < 4; ++tn) {
      const int nrow = wn * 64 + tn * 16 + l15;
      bf16x8 b0 = *(const bf16x8*)&Bh[nrow][quad * 8];
      bf16x8 b1 = *(const bf16x8*)&Bl[nrow][quad * 8];
#pragma unroll
      for (int tm = 0; tm < 4; ++tm) {
        f32x4 a = acc[tm][tn];
        a = __builtin_amdgcn_mfma_f32_16x16x32_bf16(ah[tm], b0, a, 0, 0, 0);
        a = __builtin_amdgcn_mfma_f32_16x16x32_bf16(ah[tm], b1, a, 0, 0, 0);
        a = __builtin_amdgcn_mfma_f32_16x16x32_bf16(al[tm], b0, a, 0, 0, 0);
        acc[tm][tn] = a;
      }
    }
  }
  float sum = 0.f, sq = 0.f;
#pragma unroll
  for (int tm = 0; tm < 4; ++tm) {
#pragma unroll
    for (int tn = 0; tn < 4; ++tn) {
#pragma unroll
      for (int r = 0; r < 4; ++r) {
        int m = m0 + wm * 64 + tm * 16 + quad * 4 + r;
        int n = n0 + wn * 64 + tn * 16 + l15;
        size_t idx = (size_t)m * 1024 + n;
        float o = z1[idx] + fmaxf(acc[tm][tn][r] + ffb[n], 0.f);
        s2[idx] = o;
        sum += o; sq += o * o;
      }
    }
  }
  red[tid] = make_float2(sum, sq);
  __syncthreads();
  for (int s = 128; s > 0; s >>= 1) {
    if (tid < s) { red[tid].x += red[tid + s].x; red[tid].y += red[tid + s].y; }
    __syncthreads();
  }
  if (tid == 0) part[blockIdx.x * 8 + blockIdx.y] = red[0];
}

__global__ __launch_bounds__(256) void ln_stats(
    const float2* __restrict__ part, float2* __restrict__ stats, int npart)
{
  __shared__ double sd[256], sq[256];
  const int tid = threadIdx.x;
  float2 p = (tid < npart) ? part[blockIdx.x * npart + tid] : make_float2(0.f, 0.f);
  sd[tid] = (double)p.x; sq[tid] = (double)p.y;
  __syncthreads();
  for (int s = 128; s > 0; s >>= 1) {
    if (tid < s) { sd[tid] += sd[tid + s]; sq[tid] += sq[tid + s]; }
    __syncthreads();
  }
  if (tid == 0) {
    const double n = (double)Tc * Ec;
    double mean = sd[0] / n;
    double var = sq[0] / n - mean * mean;
    if (var < 0.0) var = 0.0;
    double rs = 1.0 / sqrt(var + 1e-5);
    stats[blockIdx.x] = make_float2((float)mean, (float)rs);
  }
}

__global__ __launch_bounds__(256) void ln_norm(
    const float* __restrict__ s, const float2* __restrict__ stats,
    const float* __restrict__ w, const float* __restrict__ bias,
    float* __restrict__ out)
{
  int i = blockIdx.x * 256 + threadIdx.x;
  if (i >= (Bc * Tc * Ec) / 4) return;
  int b = i >> 18;
  int te4 = i & ((1 << 18) - 1);
  float2 st = stats[b];
  float4 sv = ((const float4*)s)[i];
  float4 wv = ((const float4*)w)[te4];
  float4 bv = ((const float4*)bias)[te4];
  float4 o;
  o.x = (sv.x - st.x) * st.y * wv.x + bv.x;
  o.y = (sv.y - st.x) * st.y * wv.y + bv.y;
  o.z = (sv.z - st.x) * st.y * wv.z + bv.z;
  o.w = (sv.w - st.x) * st.y * wv.w + bv.w;
  ((float4*)out)[i] = o;
}

// ---------------------------------------------------------------------------
extern "C" void kernel_launch(void* const* d_in, const int* in_sizes, int n_in,
                              void* d_out, int out_size, void* d_ws, size_t ws_size,
                              hipStream_t stream)
{
  const float* x    = (const float*)d_in[0];
  const float* qw   = (const float*)d_in[1];
  const float* kw   = (const float*)d_in[2];
  const float* vw   = (const float*)d_in[3];
  const float* frw  = (const float*)d_in[4];
  const float* ffw  = (const float*)d_in[5];
  const float* ffb  = (const float*)d_in[6];
  const float* ln1w = (const float*)d_in[7];
  const float* ln1b = (const float*)d_in[8];
  const float* ln2w = (const float*)d_in[9];
  const float* ln2b = (const float*)d_in[10];
  float* out = (float*)d_out;
  char* W = (char*)d_ws;

  const size_t MB = 1ull << 20;
  // Footprint: 64 MB + 16.4 KB (= round-1 proven).
  // Liveness: qf/kh/km/kl/vt live proj->attn; wT@48 dead before attn (zb
  // overlays); frT@16 after attn (kh/km dead); z1@16 after gemm_fr (frT dead);
  // s2@32 after attn (kl/vt dead).
  float*  qf  = (float*)(W);             // 16 MB fp32 [bh][t][f]
  ushort* kh  = (ushort*)(W + 16 * MB);  //  8 MB bf16 [bh][t][f]
  ushort* km  = (ushort*)(W + 24 * MB);  //  8 MB
  ushort* kl  = (ushort*)(W + 32 * MB);  //  8 MB
  ushort* vt  = (ushort*)(W + 40 * MB);  //  8 MB bf16 [bh][f][t]
  ushort* wT  = (ushort*)(W + 48 * MB);  // 14 MB — dead before attn
  float*  zb  = (float*)(W + 48 * MB);   // 16 MB fp32 [b][t][e]
  ushort* frT = (ushort*)(W + 16 * MB);  // 16 MB bf16 hi+lo — lives fr only
  float*  s1  = (float*)(W);             // aliases qf
  float*  z1  = (float*)(W + 16 * MB);   // aliases frT (after gemm_fr)
  float*  s2  = (float*)(W + 32 * MB);   // aliases kl+vt
  float2* part1  = (float2*)(W + 64 * MB);
  float2* part2  = part1 + 1024;
  float2* stats1 = part2 + 1024;
  float2* stats2 = stats1 + 4;

  transp_w<<<dim3(16, 16, 3), 256, 0, stream>>>(qw, kw, vw, wT);
  proj_qk_mfma<<<dim3(32, 8, 2), 256, 0, stream>>>(x, wT, qf, kh, km, kl);
  proj_v_mfma<<<dim3(32, 8), 256, 0, stream>>>(x, wT, vt);
  attn_mfma<<<dim3(16, 64), 256, 0, stream>>>(qf, kh, km, kl, vt, zb);
  transp_frw<<<dim3(16, 16, 4), 256, 0, stream>>>(frw, frT);
  gemm_fr_mfma<<<dim3(8, 8, 4), 256, 0, stream>>>(zb, frT, x, s1, part1);
  ln_stats<<<dim3(4), 256, 0, stream>>>(part1, stats1, 64);
  ln_norm<<<dim3(4096), 256, 0, stream>>>(s1, stats1, ln1w, ln1b, z1);
  gemm_ff_mfma<<<dim3(32, 8), 256, 0, stream>>>(z1, ffw, ffb, s2, part2);
  ln_stats<<<dim3(4), 256, 0, stream>>>(part2, stats2, 64);
  ln_norm<<<dim3(4096), 256, 0, stream>>>(s2, stats2, ln2w, ln2b, out);
}

// Round 8
// 480.736 us; speedup vs baseline: 1.0704x; 1.0704x over previous
//
#include <hip/hip_runtime.h>
#include <math.h>

constexpr int Bc = 4, Tc = 1024, Ec = 1024, Hc = 16, Fc = 64;

typedef __attribute__((ext_vector_type(8))) short bf16x8;
typedef __attribute__((ext_vector_type(4))) float f32x4;

__device__ __forceinline__ ushort f2bf(float x) {
  union { float f; unsigned u; } v; v.f = x;
  unsigned r = v.u + 0x7fffu + ((v.u >> 16) & 1u);
  return (ushort)(r >> 16);
}
__device__ __forceinline__ float bf2f(ushort h) {
  union { float f; unsigned u; } v; v.u = ((unsigned)h) << 16; return v.f;
}
__device__ __forceinline__ void split3(float x, ushort& h, ushort& m, ushort& l) {
  h = f2bf(x);
  float r1 = x - bf2f(h);
  m = f2bf(r1);
  float r2 = r1 - bf2f(m);
  l = f2bf(r2);
}
__device__ __forceinline__ void split2(float x, ushort& h, ushort& l) {
  h = f2bf(x);
  l = f2bf(x - bf2f(h));
}

// ---------------------------------------------------------------------------
// Pre-transpose + split projection weights (unchanged).
// ---------------------------------------------------------------------------
__global__ __launch_bounds__(256) void transp_w(
    const float* __restrict__ qw, const float* __restrict__ kw,
    const float* __restrict__ vw, ushort* __restrict__ wT)
{
  const int zi = blockIdx.z;
  const float* src = (zi == 0) ? qw : (zi == 1) ? kw : vw;
  ushort* dst = wT + (size_t)(zi * 3) * (1u << 20);
  const int ns = (zi == 2) ? 1 : 3;
  const int h = blockIdx.y, e0 = blockIdx.x * 64;
  __shared__ float T[64][68];
  const int tid = threadIdx.x;
  {
    const int er = tid >> 4, fr = (tid & 15) * 4;
#pragma unroll
    for (int i = 0; i < 4; ++i) {
      const float4 v = *(const float4*)&src[((size_t)(h * 1024 + e0 + er + i * 16)) * 64 + fr];
      *(float4*)&T[er + i * 16][fr] = v;
    }
  }
  __syncthreads();
  const int f = tid >> 2, eo = (tid & 3) * 16;
  ushort hs[16], ms[16], ls[16];
#pragma unroll
  for (int j = 0; j < 16; ++j) {
    split3(T[eo + j][f], hs[j], ms[j], ls[j]);
  }
  const size_t nbase = (size_t)(h * 64 + f) * 1024 + e0 + eo;
  bf16x8 v0, v1;
#pragma unroll
  for (int j = 0; j < 8; ++j) { v0[j] = (short)hs[j]; v1[j] = (short)hs[j + 8]; }
  *(bf16x8*)&dst[nbase] = v0; *(bf16x8*)&dst[nbase + 8] = v1;
  if (ns == 3) {
#pragma unroll
    for (int j = 0; j < 8; ++j) { v0[j] = (short)ms[j]; v1[j] = (short)ms[j + 8]; }
    *(bf16x8*)&dst[(1u << 20) + nbase] = v0; *(bf16x8*)&dst[(1u << 20) + nbase + 8] = v1;
#pragma unroll
    for (int j = 0; j < 8; ++j) { v0[j] = (short)ls[j]; v1[j] = (short)ls[j + 8]; }
    *(bf16x8*)&dst[(2u << 20) + nbase] = v0; *(bf16x8*)&dst[(2u << 20) + nbase + 8] = v1;
  }
}

// ---------------------------------------------------------------------------
// Pre-transpose + split2 fr weights (unchanged).
// ---------------------------------------------------------------------------
__global__ __launch_bounds__(256) void transp_frw(
    const float* __restrict__ frw, ushort* __restrict__ frT)
{
  const int bb = blockIdx.z;
  const int e0 = blockIdx.x * 64, d0 = blockIdx.y * 64;
  __shared__ float T[64][68];
  const int tid = threadIdx.x;
  {
    const int er = tid >> 4, dr = (tid & 15) * 4;
#pragma unroll
    for (int i = 0; i < 4; ++i) {
      const float4 v = *(const float4*)&frw[((size_t)bb * 1024 + e0 + er + i * 16) * 1024 + d0 + dr];
      *(float4*)&T[er + i * 16][dr] = v;
    }
  }
  __syncthreads();
  const int d = tid >> 2, eo = (tid & 3) * 16;
  ushort hs[16], ls[16];
#pragma unroll
  for (int j = 0; j < 16; ++j) split2(T[eo + j][d], hs[j], ls[j]);
  const size_t nbase = ((size_t)bb * 1024 + d0 + d) * 1024 + e0 + eo;
  bf16x8 v0, v1;
#pragma unroll
  for (int j = 0; j < 8; ++j) { v0[j] = (short)hs[j]; v1[j] = (short)hs[j + 8]; }
  *(bf16x8*)&frT[nbase] = v0; *(bf16x8*)&frT[nbase + 8] = v1;
#pragma unroll
  for (int j = 0; j < 8; ++j) { v0[j] = (short)ls[j]; v1[j] = (short)ls[j + 8]; }
  *(bf16x8*)&frT[(4u << 20) + nbase] = v0; *(bf16x8*)&frT[(4u << 20) + nbase + 8] = v1;
}

// ---------------------------------------------------------------------------
// q/k projection MFMA (unchanged from round 7).
// ---------------------------------------------------------------------------
__global__ __launch_bounds__(256) void proj_qk_mfma(
    const float* __restrict__ x, const ushort* __restrict__ wT,
    float* __restrict__ qf, ushort* __restrict__ kh,
    ushort* __restrict__ km, ushort* __restrict__ kl)
{
  const int zi = blockIdx.z;
  const ushort* wt = wT + (size_t)zi * 3 * (1u << 20);
  const int m0 = blockIdx.x * 128, n0 = blockIdx.y * 128;
  __shared__ ushort As[3][128][36];
  __shared__ ushort Bs[3][128][36];
  const int tid = threadIdx.x;
  const int wave = tid >> 6, lane = tid & 63, l15 = lane & 15, quad = lane >> 4;
  const int wm = wave >> 1, wn = wave & 1;
  const int sr = tid >> 1, sk = (tid & 1) * 16;
  f32x4 acc[4][4] = {};
  for (int k0 = 0; k0 < 1024; k0 += 32) {
    __syncthreads();
    {
      const float* ap = x + (size_t)(m0 + sr) * 1024 + k0 + sk;
      float xs[16];
      *(float4*)&xs[0]  = *(const float4*)(ap);
      *(float4*)&xs[4]  = *(const float4*)(ap + 4);
      *(float4*)&xs[8]  = *(const float4*)(ap + 8);
      *(float4*)&xs[12] = *(const float4*)(ap + 12);
      bf16x8 h0, h1, m0v, m1v, l0, l1;
#pragma unroll
      for (int j = 0; j < 8; ++j) {
        ushort hu, mu, lu;
        split3(xs[j], hu, mu, lu);
        h0[j] = (short)hu; m0v[j] = (short)mu; l0[j] = (short)lu;
        split3(xs[j + 8], hu, mu, lu);
        h1[j] = (short)hu; m1v[j] = (short)mu; l1[j] = (short)lu;
      }
      *(bf16x8*)&As[0][sr][sk] = h0;  *(bf16x8*)&As[0][sr][sk + 8] = h1;
      *(bf16x8*)&As[1][sr][sk] = m0v; *(bf16x8*)&As[1][sr][sk + 8] = m1v;
      *(bf16x8*)&As[2][sr][sk] = l0;  *(bf16x8*)&As[2][sr][sk + 8] = l1;
#pragma unroll
      for (int s = 0; s < 3; ++s) {
        const ushort* bp = wt + ((size_t)s << 20) + (size_t)(n0 + sr) * 1024 + k0 + sk;
        *(bf16x8*)&Bs[s][sr][sk]     = *(const bf16x8*)(bp);
        *(bf16x8*)&Bs[s][sr][sk + 8] = *(const bf16x8*)(bp + 8);
      }
    }
    __syncthreads();
    bf16x8 af[4][3];
#pragma unroll
    for (int tm = 0; tm < 4; ++tm)
#pragma unroll
      for (int s = 0; s < 3; ++s)
        af[tm][s] = *(const bf16x8*)&As[s][wm * 64 + tm * 16 + l15][quad * 8];
#pragma unroll
    for (int tn = 0; tn < 4; ++tn) {
      const int nrow = wn * 64 + tn * 16 + l15;
      bf16x8 b0 = *(const bf16x8*)&Bs[0][nrow][quad * 8];
      bf16x8 b1 = *(const bf16x8*)&Bs[1][nrow][quad * 8];
      bf16x8 b2 = *(const bf16x8*)&Bs[2][nrow][quad * 8];
#pragma unroll
      for (int tm = 0; tm < 4; ++tm) {
        f32x4 a = acc[tm][tn];
        a = __builtin_amdgcn_mfma_f32_16x16x32_bf16(af[tm][0], b0, a, 0, 0, 0);
        a = __builtin_amdgcn_mfma_f32_16x16x32_bf16(af[tm][0], b1, a, 0, 0, 0);
        a = __builtin_amdgcn_mfma_f32_16x16x32_bf16(af[tm][1], b0, a, 0, 0, 0);
        a = __builtin_amdgcn_mfma_f32_16x16x32_bf16(af[tm][0], b2, a, 0, 0, 0);
        a = __builtin_amdgcn_mfma_f32_16x16x32_bf16(af[tm][1], b1, a, 0, 0, 0);
        a = __builtin_amdgcn_mfma_f32_16x16x32_bf16(af[tm][2], b0, a, 0, 0, 0);
        acc[tm][tn] = a;
      }
    }
  }
#pragma unroll
  for (int tm = 0; tm < 4; ++tm) {
#pragma unroll
    for (int tn = 0; tn < 4; ++tn) {
#pragma unroll
      for (int r = 0; r < 4; ++r) {
        int m = m0 + wm * 64 + tm * 16 + quad * 4 + r;
        int n = n0 + wn * 64 + tn * 16 + l15;
        int b = m >> 10, t = m & 1023, h = n >> 6, f = n & 63;
        size_t idx = (((size_t)(b * 16 + h)) * 1024 + t) * 64 + f;
        if (zi == 0) {
          qf[idx] = acc[tm][tn][r];
        } else {
          ushort hu, mu, lu;
          split3(acc[tm][tn][r], hu, mu, lu);
          kh[idx] = hu; km[idx] = mu; kl[idx] = lu;
        }
      }
    }
  }
}

// ---------------------------------------------------------------------------
// v projection MFMA (unchanged).
// ---------------------------------------------------------------------------
__global__ __launch_bounds__(256) void proj_v_mfma(
    const float* __restrict__ x, const ushort* __restrict__ wT,
    ushort* __restrict__ vt)
{
  const ushort* wt = wT + (size_t)6 * (1u << 20);
  const int m0 = blockIdx.x * 128, n0 = blockIdx.y * 128;
  __shared__ ushort As[128][36];
  __shared__ ushort Bs[128][36];
  const int tid = threadIdx.x;
  const int wave = tid >> 6, lane = tid & 63, l15 = lane & 15, quad = lane >> 4;
  const int wm = wave >> 1, wn = wave & 1;
  const int sr = tid >> 1, sk = (tid & 1) * 16;
  f32x4 acc[4][4] = {};
  for (int k0 = 0; k0 < 1024; k0 += 32) {
    __syncthreads();
    {
      const float* ap = x + (size_t)(m0 + sr) * 1024 + k0 + sk;
      float xs[16];
      *(float4*)&xs[0]  = *(const float4*)(ap);
      *(float4*)&xs[4]  = *(const float4*)(ap + 4);
      *(float4*)&xs[8]  = *(const float4*)(ap + 8);
      *(float4*)&xs[12] = *(const float4*)(ap + 12);
      bf16x8 h0, h1;
#pragma unroll
      for (int j = 0; j < 8; ++j) {
        h0[j] = (short)f2bf(xs[j]);
        h1[j] = (short)f2bf(xs[j + 8]);
      }
      *(bf16x8*)&As[sr][sk] = h0; *(bf16x8*)&As[sr][sk + 8] = h1;
      const ushort* bp = wt + (size_t)(n0 + sr) * 1024 + k0 + sk;
      *(bf16x8*)&Bs[sr][sk]     = *(const bf16x8*)(bp);
      *(bf16x8*)&Bs[sr][sk + 8] = *(const bf16x8*)(bp + 8);
    }
    __syncthreads();
    bf16x8 af[4];
#pragma unroll
    for (int tm = 0; tm < 4; ++tm)
      af[tm] = *(const bf16x8*)&As[wm * 64 + tm * 16 + l15][quad * 8];
#pragma unroll
    for (int tn = 0; tn < 4; ++tn) {
      bf16x8 b0 = *(const bf16x8*)&Bs[wn * 64 + tn * 16 + l15][quad * 8];
#pragma unroll
      for (int tm = 0; tm < 4; ++tm)
        acc[tm][tn] = __builtin_amdgcn_mfma_f32_16x16x32_bf16(af[tm], b0, acc[tm][tn], 0, 0, 0);
    }
  }
#pragma unroll
  for (int tm = 0; tm < 4; ++tm) {
#pragma unroll
    for (int tn = 0; tn < 4; ++tn) {
#pragma unroll
      for (int r = 0; r < 4; ++r) {
        int m = m0 + wm * 64 + tm * 16 + quad * 4 + r;
        int n = n0 + wn * 64 + tn * 16 + l15;
        int b = m >> 10, t = m & 1023, h = n >> 6, f = n & 63;
        vt[(((size_t)(b * 16 + h)) * 64 + f) * 1024 + t] = f2bf(acc[tm][tn][r]);
      }
    }
  }
}

// ---------------------------------------------------------------------------
// Flash attention: Q-tile 128, 512 threads = 8 waves x 16 rows. Per-wave math
// bit-identical to round 7; K/V staged once per 128 rows (half the re-reads),
// 2x MFMA per barrier window. Grid (T/128, B*H) = (8, 64).
// ---------------------------------------------------------------------------
__global__ __launch_bounds__(512) void attn_mfma(
    const float* __restrict__ qf, const ushort* __restrict__ kh,
    const ushort* __restrict__ km, const ushort* __restrict__ kl,
    const ushort* __restrict__ vt, float* __restrict__ z)
{
  __shared__ ushort Ks[3][64][68];
  __shared__ ushort Vs[64][68];
  __shared__ ushort Pl[8][16][68];

  const int tid = threadIdx.x;
  const int wave = tid >> 6, lane = tid & 63;
  const int l15 = lane & 15, quad = lane >> 4;
  const int bh = blockIdx.y;
  const int qbase = blockIdx.x * 128;

  bf16x8 aqh[2], aqm[2], aql[2];
  {
    const int qrow = qbase + wave * 16 + l15;
    const float* qp = qf + ((size_t)bh * Tc + qrow) * Fc;
#pragma unroll
    for (int ks = 0; ks < 2; ++ks) {
      int f0 = ks * 32 + quad * 8;
      float4 x0 = *(const float4*)(qp + f0);
      float4 x1 = *(const float4*)(qp + f0 + 4);
      float xs[8] = {x0.x, x0.y, x0.z, x0.w, x1.x, x1.y, x1.z, x1.w};
#pragma unroll
      for (int j = 0; j < 8; ++j) {
        ushort hu, mu, lu;
        split3(xs[j], hu, mu, lu);
        aqh[ks][j] = (short)hu; aqm[ks][j] = (short)mu; aql[ks][j] = (short)lu;
      }
    }
  }

  f32x4 o[4] = {{0,0,0,0},{0,0,0,0},{0,0,0,0},{0,0,0,0}};
  float m_run[4], l_run[4];
#pragma unroll
  for (int r = 0; r < 4; ++r) { m_run[r] = -1e30f; l_run[r] = 0.f; }

  // staging: 512 threads cover 4 tiles (Ks0/Ks1/Ks2/Vs) of 64x64 ushorts,
  // one bf16x8 each: srow = tid>>3 (0..63), sc8 = tid&7 (col = sc8*8).
  const int srow = tid >> 3, sc8 = tid & 7;
  const size_t kbase = (size_t)bh * Tc * Fc;
  const size_t vbase = (size_t)bh * Fc * Tc;
  const ushort* kp0 = kh + kbase + (size_t)srow * Fc + sc8 * 8;
  const ushort* kp1 = km + kbase + (size_t)srow * Fc + sc8 * 8;
  const ushort* kp2 = kl + kbase + (size_t)srow * Fc + sc8 * 8;
  const ushort* vp  = vt + vbase + (size_t)srow * Tc + sc8 * 8;

  for (int kt = 0; kt < Tc; kt += 64) {
    __syncthreads();
    {
      const size_t ko = (size_t)kt * Fc;
      *(bf16x8*)&Ks[0][srow][sc8 * 8] = *(const bf16x8*)(kp0 + ko);
      *(bf16x8*)&Ks[1][srow][sc8 * 8] = *(const bf16x8*)(kp1 + ko);
      *(bf16x8*)&Ks[2][srow][sc8 * 8] = *(const bf16x8*)(kp2 + ko);
      *(bf16x8*)&Vs[srow][sc8 * 8]    = *(const bf16x8*)(vp + kt);
    }
    __syncthreads();

    f32x4 sacc[4] = {{0,0,0,0},{0,0,0,0},{0,0,0,0},{0,0,0,0}};
#pragma unroll
    for (int nt = 0; nt < 4; ++nt) {
      int key = nt * 16 + l15;
#pragma unroll
      for (int ks = 0; ks < 2; ++ks) {
        int f0 = ks * 32 + quad * 8;
        bf16x8 bh_ = *(const bf16x8*)&Ks[0][key][f0];
        bf16x8 bm_ = *(const bf16x8*)&Ks[1][key][f0];
        bf16x8 bl_ = *(const bf16x8*)&Ks[2][key][f0];
        sacc[nt] = __builtin_amdgcn_mfma_f32_16x16x32_bf16(aqh[ks], bh_, sacc[nt], 0, 0, 0);
        sacc[nt] = __builtin_amdgcn_mfma_f32_16x16x32_bf16(aqh[ks], bm_, sacc[nt], 0, 0, 0);
        sacc[nt] = __builtin_amdgcn_mfma_f32_16x16x32_bf16(aqm[ks], bh_, sacc[nt], 0, 0, 0);
        sacc[nt] = __builtin_amdgcn_mfma_f32_16x16x32_bf16(aqh[ks], bl_, sacc[nt], 0, 0, 0);
        sacc[nt] = __builtin_amdgcn_mfma_f32_16x16x32_bf16(aqm[ks], bm_, sacc[nt], 0, 0, 0);
        sacc[nt] = __builtin_amdgcn_mfma_f32_16x16x32_bf16(aql[ks], bh_, sacc[nt], 0, 0, 0);
      }
    }

    const int rowg0 = qbase + wave * 16 + quad * 4;
    float mx[4];
#pragma unroll
    for (int r = 0; r < 4; ++r) mx[r] = -1e30f;
#pragma unroll
    for (int nt = 0; nt < 4; ++nt) {
      int key = kt + nt * 16 + l15;
#pragma unroll
      for (int r = 0; r < 4; ++r) {
        float s = sacc[nt][r];
        if (key > rowg0 + r) s *= -1.0e9f + 1.0f;
        s *= 0.125f;
        sacc[nt][r] = s;
        mx[r] = fmaxf(mx[r], s);
      }
    }
#pragma unroll
    for (int r = 0; r < 4; ++r)
#pragma unroll
      for (int d = 1; d < 16; d <<= 1) mx[r] = fmaxf(mx[r], __shfl_xor(mx[r], d));

    float corr[4], ps[4];
#pragma unroll
    for (int r = 0; r < 4; ++r) {
      float m2 = fmaxf(m_run[r], mx[r]);
      corr[r] = __expf(m_run[r] - m2);
      m_run[r] = m2;
      ps[r] = 0.f;
    }
#pragma unroll
    for (int nt = 0; nt < 4; ++nt) {
#pragma unroll
      for (int r = 0; r < 4; ++r) {
        float p = __expf(sacc[nt][r] - m_run[r]);
        ps[r] += p;
        Pl[wave][quad * 4 + r][nt * 16 + l15] = f2bf(p);
      }
    }
#pragma unroll
    for (int r = 0; r < 4; ++r) {
#pragma unroll
      for (int d = 1; d < 16; d <<= 1) ps[r] += __shfl_xor(ps[r], d);
      l_run[r] = l_run[r] * corr[r] + ps[r];
#pragma unroll
      for (int ft = 0; ft < 4; ++ft) o[ft][r] *= corr[r];
    }

#pragma unroll
    for (int ks2 = 0; ks2 < 2; ++ks2) {
      bf16x8 pa = *(const bf16x8*)&Pl[wave][l15][ks2 * 32 + quad * 8];
#pragma unroll
      for (int ft = 0; ft < 4; ++ft) {
        bf16x8 vb = *(const bf16x8*)&Vs[ft * 16 + l15][ks2 * 32 + quad * 8];
        o[ft] = __builtin_amdgcn_mfma_f32_16x16x32_bf16(pa, vb, o[ft], 0, 0, 0);
      }
    }
  }

  const int b = bh >> 4, h = bh & 15;
#pragma unroll
  for (int r = 0; r < 4; ++r) {
    float inv = 1.f / l_run[r];
    int row = qbase + wave * 16 + quad * 4 + r;
    float* zp = z + ((size_t)(b * Tc + row)) * Ec + h * Fc;
#pragma unroll
    for (int ft = 0; ft < 4; ++ft) zp[ft * 16 + l15] = o[ft][r] * inv;
  }
}

// ---------------------------------------------------------------------------
// fr GEMM, split2 MFMA (unchanged).
// ---------------------------------------------------------------------------
__global__ __launch_bounds__(256) void gemm_fr_mfma(
    const float* __restrict__ z, const ushort* __restrict__ frT,
    const float* __restrict__ x, float* __restrict__ s1,
    float2* __restrict__ part)
{
  const int bb = blockIdx.z;
  const int m0 = blockIdx.x * 128, n0 = blockIdx.y * 128;
  __shared__ ushort Ah[128][36], Al[128][36];
  __shared__ ushort Bh[128][36], Bl[128][36];
  __shared__ float2 red[256];
  const int tid = threadIdx.x;
  const int wave = tid >> 6, lane = tid & 63, l15 = lane & 15, quad = lane >> 4;
  const int wm = wave >> 1, wn = wave & 1;
  const int sr = tid >> 1, sk = (tid & 1) * 16;
  f32x4 acc[4][4] = {};
  const ushort* bhp = frT + ((size_t)bb * 1024 + n0) * 1024;
  const ushort* blp = bhp + (4u << 20);
  for (int k0 = 0; k0 < 1024; k0 += 32) {
    __syncthreads();
    {
      const float* ap = z + ((size_t)bb * 1024 + m0 + sr) * 1024 + k0 + sk;
      float xs[16];
      *(float4*)&xs[0]  = *(const float4*)(ap);
      *(float4*)&xs[4]  = *(const float4*)(ap + 4);
      *(float4*)&xs[8]  = *(const float4*)(ap + 8);
      *(float4*)&xs[12] = *(const float4*)(ap + 12);
      bf16x8 h0, h1, l0, l1;
#pragma unroll
      for (int j = 0; j < 8; ++j) {
        ushort hu, lu;
        split2(xs[j], hu, lu);     h0[j] = (short)hu; l0[j] = (short)lu;
        split2(xs[j + 8], hu, lu); h1[j] = (short)hu; l1[j] = (short)lu;
      }
      *(bf16x8*)&Ah[sr][sk] = h0; *(bf16x8*)&Ah[sr][sk + 8] = h1;
      *(bf16x8*)&Al[sr][sk] = l0; *(bf16x8*)&Al[sr][sk + 8] = l1;
      const size_t boff = (size_t)sr * 1024 + k0 + sk;
      *(bf16x8*)&Bh[sr][sk]     = *(const bf16x8*)(bhp + boff);
      *(bf16x8*)&Bh[sr][sk + 8] = *(const bf16x8*)(bhp + boff + 8);
      *(bf16x8*)&Bl[sr][sk]     = *(const bf16x8*)(blp + boff);
      *(bf16x8*)&Bl[sr][sk + 8] = *(const bf16x8*)(blp + boff + 8);
    }
    __syncthreads();
    bf16x8 ah[4], al[4];
#pragma unroll
    for (int tm = 0; tm < 4; ++tm) {
      ah[tm] = *(const bf16x8*)&Ah[wm * 64 + tm * 16 + l15][quad * 8];
      al[tm] = *(const bf16x8*)&Al[wm * 64 + tm * 16 + l15][quad * 8];
    }
#pragma unroll
    for (int tn = 0; tn < 4; ++tn) {
      const int nrow = wn * 64 + tn * 16 + l15;
      bf16x8 b0 = *(const bf16x8*)&Bh[nrow][quad * 8];
      bf16x8 b1 = *(const bf16x8*)&Bl[nrow][quad * 8];
#pragma unroll
      for (int tm = 0; tm < 4; ++tm) {
        f32x4 a = acc[tm][tn];
        a = __builtin_amdgcn_mfma_f32_16x16x32_bf16(ah[tm], b0, a, 0, 0, 0);
        a = __builtin_amdgcn_mfma_f32_16x16x32_bf16(ah[tm], b1, a, 0, 0, 0);
        a = __builtin_amdgcn_mfma_f32_16x16x32_bf16(al[tm], b0, a, 0, 0, 0);
        acc[tm][tn] = a;
      }
    }
  }
  float sum = 0.f, sq = 0.f;
#pragma unroll
  for (int tm = 0; tm < 4; ++tm) {
#pragma unroll
    for (int tn = 0; tn < 4; ++tn) {
#pragma unroll
      for (int r = 0; r < 4; ++r) {
        int m = m0 + wm * 64 + tm * 16 + quad * 4 + r;
        int n = n0 + wn * 64 + tn * 16 + l15;
        size_t idx = ((size_t)bb * 1024 + m) * 1024 + n;
        float o = x[idx] + acc[tm][tn][r];
        s1[idx] = o;
        sum += o; sq += o * o;
      }
    }
  }
  red[tid] = make_float2(sum, sq);
  __syncthreads();
  for (int s = 128; s > 0; s >>= 1) {
    if (tid < s) { red[tid].x += red[tid + s].x; red[tid].y += red[tid + s].y; }
    __syncthreads();
  }
  if (tid == 0) part[(bb * 8 + blockIdx.x) * 8 + blockIdx.y] = red[0];
}

// ---------------------------------------------------------------------------
// ff GEMM, split2 MFMA (unchanged).
// ---------------------------------------------------------------------------
__global__ __launch_bounds__(256) void gemm_ff_mfma(
    const float* __restrict__ z1, const float* __restrict__ ffw,
    const float* __restrict__ ffb, float* __restrict__ s2,
    float2* __restrict__ part)
{
  const int m0 = blockIdx.x * 128, n0 = blockIdx.y * 128;
  __shared__ ushort Ah[128][36], Al[128][36];
  __shared__ ushort Bh[128][36], Bl[128][36];
  __shared__ float2 red[256];
  const int tid = threadIdx.x;
  const int wave = tid >> 6, lane = tid & 63, l15 = lane & 15, quad = lane >> 4;
  const int wm = wave >> 1, wn = wave & 1;
  const int sr = tid >> 1, sk = (tid & 1) * 16;
  f32x4 acc[4][4] = {};
  for (int k0 = 0; k0 < 1024; k0 += 32) {
    __syncthreads();
    {
      const float* ap = z1 + (size_t)(m0 + sr) * 1024 + k0 + sk;
      const float* bp = ffw + (size_t)(n0 + sr) * 1024 + k0 + sk;
      float xs[16], ys[16];
      *(float4*)&xs[0]  = *(const float4*)(ap);
      *(float4*)&xs[4]  = *(const float4*)(ap + 4);
      *(float4*)&xs[8]  = *(const float4*)(ap + 8);
      *(float4*)&xs[12] = *(const float4*)(ap + 12);
      *(float4*)&ys[0]  = *(const float4*)(bp);
      *(float4*)&ys[4]  = *(const float4*)(bp + 4);
      *(float4*)&ys[8]  = *(const float4*)(bp + 8);
      *(float4*)&ys[12] = *(const float4*)(bp + 12);
      bf16x8 h0, h1, l0, l1, g0, g1, e0, e1;
#pragma unroll
      for (int j = 0; j < 8; ++j) {
        ushort hu, lu;
        split2(xs[j], hu, lu);     h0[j] = (short)hu; l0[j] = (short)lu;
        split2(xs[j + 8], hu, lu); h1[j] = (short)hu; l1[j] = (short)lu;
        split2(ys[j], hu, lu);     g0[j] = (short)hu; e0[j] = (short)lu;
        split2(ys[j + 8], hu, lu); g1[j] = (short)hu; e1[j] = (short)lu;
      }
      *(bf16x8*)&Ah[sr][sk] = h0; *(bf16x8*)&Ah[sr][sk + 8] = h1;
      *(bf16x8*)&Al[sr][sk] = l0; *(bf16x8*)&Al[sr][sk + 8] = l1;
      *(bf16x8*)&Bh[sr][sk] = g0; *(bf16x8*)&Bh[sr][sk + 8] = g1;
      *(bf16x8*)&Bl[sr][sk] = e0; *(bf16x8*)&Bl[sr][sk + 8] = e1;
    }
    __syncthreads();
    bf16x8 ah[4], al[4];
#pragma unroll
    for (int tm = 0; tm < 4; ++tm) {
      ah[tm] = *(const bf16x8*)&Ah[wm * 64 + tm * 16 + l15][quad * 8];
      al[tm] = *(const bf16x8*)&Al[wm * 64 + tm * 16 + l15][quad * 8];
    }
#pragma unroll
    for (int tn = 0; tn < 4; ++tn) {
      const int nrow = wn * 64 + tn * 16 + l15;
      bf16x8 b0 = *(const bf16x8*)&Bh[nrow][quad * 8];
      bf16x8 b1 = *(const bf16x8*)&Bl[nrow][quad * 8];
#pragma unroll
      for (int tm = 0; tm < 4; ++tm) {
        f32x4 a = acc[tm][tn];
        a = __builtin_amdgcn_mfma_f32_16x16x32_bf16(ah[tm], b0, a, 0, 0, 0);
        a = __builtin_amdgcn_mfma_f32_16x16x32_bf16(ah[tm], b1, a, 0, 0, 0);
        a = __builtin_amdgcn_mfma_f32_16x16x32_bf16(al[tm], b0, a, 0, 0, 0);
        acc[tm][tn] = a;
      }
    }
  }
  float sum = 0.f, sq = 0.f;
#pragma unroll
  for (int tm = 0; tm < 4; ++tm) {
#pragma unroll
    for (int tn = 0; tn < 4; ++tn) {
#pragma unroll
      for (int r = 0; r < 4; ++r) {
        int m = m0 + wm * 64 + tm * 16 + quad * 4 + r;
        int n = n0 + wn * 64 + tn * 16 + l15;
        size_t idx = (size_t)m * 1024 + n;
        float o = z1[idx] + fmaxf(acc[tm][tn][r] + ffb[n], 0.f);
        s2[idx] = o;
        sum += o; sq += o * o;
      }
    }
  }
  red[tid] = make_float2(sum, sq);
  __syncthreads();
  for (int s = 128; s > 0; s >>= 1) {
    if (tid < s) { red[tid].x += red[tid + s].x; red[tid].y += red[tid + s].y; }
    __syncthreads();
  }
  if (tid == 0) part[blockIdx.x * 8 + blockIdx.y] = red[0];
}

__global__ __launch_bounds__(256) void ln_stats(
    const float2* __restrict__ part, float2* __restrict__ stats, int npart)
{
  __shared__ double sd[256], sq[256];
  const int tid = threadIdx.x;
  float2 p = (tid < npart) ? part[blockIdx.x * npart + tid] : make_float2(0.f, 0.f);
  sd[tid] = (double)p.x; sq[tid] = (double)p.y;
  __syncthreads();
  for (int s = 128; s > 0; s >>= 1) {
    if (tid < s) { sd[tid] += sd[tid + s]; sq[tid] += sq[tid + s]; }
    __syncthreads();
  }
  if (tid == 0) {
    const double n = (double)Tc * Ec;
    double mean = sd[0] / n;
    double var = sq[0] / n - mean * mean;
    if (var < 0.0) var = 0.0;
    double rs = 1.0 / sqrt(var + 1e-5);
    stats[blockIdx.x] = make_float2((float)mean, (float)rs);
  }
}

__global__ __launch_bounds__(256) void ln_norm(
    const float* __restrict__ s, const float2* __restrict__ stats,
    const float* __restrict__ w, const float* __restrict__ bias,
    float* __restrict__ out)
{
  int i = blockIdx.x * 256 + threadIdx.x;
  if (i >= (Bc * Tc * Ec) / 4) return;
  int b = i >> 18;
  int te4 = i & ((1 << 18) - 1);
  float2 st = stats[b];
  float4 sv = ((const float4*)s)[i];
  float4 wv = ((const float4*)w)[te4];
  float4 bv = ((const float4*)bias)[te4];
  float4 o;
  o.x = (sv.x - st.x) * st.y * wv.x + bv.x;
  o.y = (sv.y - st.x) * st.y * wv.y + bv.y;
  o.z = (sv.z - st.x) * st.y * wv.z + bv.z;
  o.w = (sv.w - st.x) * st.y * wv.w + bv.w;
  ((float4*)out)[i] = o;
}

// ---------------------------------------------------------------------------
extern "C" void kernel_launch(void* const* d_in, const int* in_sizes, int n_in,
                              void* d_out, int out_size, void* d_ws, size_t ws_size,
                              hipStream_t stream)
{
  const float* x    = (const float*)d_in[0];
  const float* qw   = (const float*)d_in[1];
  const float* kw   = (const float*)d_in[2];
  const float* vw   = (const float*)d_in[3];
  const float* frw  = (const float*)d_in[4];
  const float* ffw  = (const float*)d_in[5];
  const float* ffb  = (const float*)d_in[6];
  const float* ln1w = (const float*)d_in[7];
  const float* ln1b = (const float*)d_in[8];
  const float* ln2w = (const float*)d_in[9];
  const float* ln2b = (const float*)d_in[10];
  float* out = (float*)d_out;
  char* W = (char*)d_ws;

  const size_t MB = 1ull << 20;
  // Footprint: 64 MB + 16.4 KB (= round-1 proven). Same layout as round 7.
  float*  qf  = (float*)(W);             // 16 MB fp32 [bh][t][f]
  ushort* kh  = (ushort*)(W + 16 * MB);  //  8 MB bf16 [bh][t][f]
  ushort* km  = (ushort*)(W + 24 * MB);  //  8 MB
  ushort* kl  = (ushort*)(W + 32 * MB);  //  8 MB
  ushort* vt  = (ushort*)(W + 40 * MB);  //  8 MB bf16 [bh][f][t]
  ushort* wT  = (ushort*)(W + 48 * MB);  // 14 MB — dead before attn
  float*  zb  = (float*)(W + 48 * MB);   // 16 MB fp32 [b][t][e]
  ushort* frT = (ushort*)(W + 16 * MB);  // 16 MB bf16 hi+lo — lives fr only
  float*  s1  = (float*)(W);             // aliases qf
  float*  z1  = (float*)(W + 16 * MB);   // aliases frT (after gemm_fr)
  float*  s2  = (float*)(W + 32 * MB);   // aliases kl+vt
  float2* part1  = (float2*)(W + 64 * MB);
  float2* part2  = part1 + 1024;
  float2* stats1 = part2 + 1024;
  float2* stats2 = stats1 + 4;

  transp_w<<<dim3(16, 16, 3), 256, 0, stream>>>(qw, kw, vw, wT);
  proj_qk_mfma<<<dim3(32, 8, 2), 256, 0, stream>>>(x, wT, qf, kh, km, kl);
  proj_v_mfma<<<dim3(32, 8), 256, 0, stream>>>(x, wT, vt);
  attn_mfma<<<dim3(8, 64), 512, 0, stream>>>(qf, kh, km, kl, vt, zb);
  transp_frw<<<dim3(16, 16, 4), 256, 0, stream>>>(frw, frT);
  gemm_fr_mfma<<<dim3(8, 8, 4), 256, 0, stream>>>(zb, frT, x, s1, part1);
  ln_stats<<<dim3(4), 256, 0, stream>>>(part1, stats1, 64);
  ln_norm<<<dim3(4096), 256, 0, stream>>>(s1, stats1, ln1w, ln1b, z1);
  gemm_ff_mfma<<<dim3(32, 8), 256, 0, stream>>>(z1, ffw, ffb, s2, part2);
  ln_stats<<<dim3(4), 256, 0, stream>>>(part2, stats2, 64);
  ln_norm<<<dim3(4096), 256, 0, stream>>>(s2, stats2, ln2w, ln2b, out);
}

// Round 9
// 446.496 us; speedup vs baseline: 1.1525x; 1.0767x over previous
//
#include <hip/hip_runtime.h>
#include <math.h>

constexpr int Bc = 4, Tc = 1024, Ec = 1024, Hc = 16, Fc = 64;

typedef __attribute__((ext_vector_type(8))) short bf16x8;
typedef __attribute__((ext_vector_type(4))) float f32x4;

__device__ __forceinline__ ushort f2bf(float x) {
  union { float f; unsigned u; } v; v.f = x;
  unsigned r = v.u + 0x7fffu + ((v.u >> 16) & 1u);
  return (ushort)(r >> 16);
}
__device__ __forceinline__ float bf2f(ushort h) {
  union { float f; unsigned u; } v; v.u = ((unsigned)h) << 16; return v.f;
}
__device__ __forceinline__ void split3(float x, ushort& h, ushort& m, ushort& l) {
  h = f2bf(x);
  float r1 = x - bf2f(h);
  m = f2bf(r1);
  float r2 = r1 - bf2f(m);
  l = f2bf(r2);
}
__device__ __forceinline__ void split2(float x, ushort& h, ushort& l) {
  h = f2bf(x);
  l = f2bf(x - bf2f(h));
}
// Truncation split3: ~8 VALU ops (vs ~19). One-sided residual < 2^-22 rel —
// score-error ~0.01, far inside the masked-argmin flip budget (~1).
__device__ __forceinline__ void split3t(float x, ushort& h, ushort& m, ushort& l) {
  union { float f; unsigned u; } v; v.f = x;
  h = (ushort)(v.u >> 16);
  union { float f; unsigned u; } hf; hf.u = v.u & 0xffff0000u;
  float r1 = x - hf.f;
  union { float f; unsigned u; } v1; v1.f = r1;
  m = (ushort)(v1.u >> 16);
  union { float f; unsigned u; } mf; mf.u = v1.u & 0xffff0000u;
  float r2 = r1 - mf.f;
  union { float f; unsigned u; } v2; v2.f = r2;
  l = (ushort)(v2.u >> 16);
}

// Fragment-major LDS cell: [tile(0..7)][quad(0..3)][lane(0..15)][8 ushorts]
// reads are lane-sequential (conflict-free); writes 2-way (free).
#define FRAG_IDX(tile, quad, l) (((((tile) * 4) + (quad)) * 16 + (l)) * 8)

// ---------------------------------------------------------------------------
// Pre-transpose + split projection weights (unchanged).
// ---------------------------------------------------------------------------
__global__ __launch_bounds__(256) void transp_w(
    const float* __restrict__ qw, const float* __restrict__ kw,
    const float* __restrict__ vw, ushort* __restrict__ wT)
{
  const int zi = blockIdx.z;
  const float* src = (zi == 0) ? qw : (zi == 1) ? kw : vw;
  ushort* dst = wT + (size_t)(zi * 3) * (1u << 20);
  const int ns = (zi == 2) ? 1 : 3;
  const int h = blockIdx.y, e0 = blockIdx.x * 64;
  __shared__ float T[64][68];
  const int tid = threadIdx.x;
  {
    const int er = tid >> 4, fr = (tid & 15) * 4;
#pragma unroll
    for (int i = 0; i < 4; ++i) {
      const float4 v = *(const float4*)&src[((size_t)(h * 1024 + e0 + er + i * 16)) * 64 + fr];
      *(float4*)&T[er + i * 16][fr] = v;
    }
  }
  __syncthreads();
  const int f = tid >> 2, eo = (tid & 3) * 16;
  ushort hs[16], ms[16], ls[16];
#pragma unroll
  for (int j = 0; j < 16; ++j) split3(T[eo + j][f], hs[j], ms[j], ls[j]);
  const size_t nbase = (size_t)(h * 64 + f) * 1024 + e0 + eo;
  bf16x8 v0, v1;
#pragma unroll
  for (int j = 0; j < 8; ++j) { v0[j] = (short)hs[j]; v1[j] = (short)hs[j + 8]; }
  *(bf16x8*)&dst[nbase] = v0; *(bf16x8*)&dst[nbase + 8] = v1;
  if (ns == 3) {
#pragma unroll
    for (int j = 0; j < 8; ++j) { v0[j] = (short)ms[j]; v1[j] = (short)ms[j + 8]; }
    *(bf16x8*)&dst[(1u << 20) + nbase] = v0; *(bf16x8*)&dst[(1u << 20) + nbase + 8] = v1;
#pragma unroll
    for (int j = 0; j < 8; ++j) { v0[j] = (short)ls[j]; v1[j] = (short)ls[j + 8]; }
    *(bf16x8*)&dst[(2u << 20) + nbase] = v0; *(bf16x8*)&dst[(2u << 20) + nbase + 8] = v1;
  }
}

// ---------------------------------------------------------------------------
// Pre-transpose + split2 fr weights (unchanged).
// ---------------------------------------------------------------------------
__global__ __launch_bounds__(256) void transp_frw(
    const float* __restrict__ frw, ushort* __restrict__ frT)
{
  const int bb = blockIdx.z;
  const int e0 = blockIdx.x * 64, d0 = blockIdx.y * 64;
  __shared__ float T[64][68];
  const int tid = threadIdx.x;
  {
    const int er = tid >> 4, dr = (tid & 15) * 4;
#pragma unroll
    for (int i = 0; i < 4; ++i) {
      const float4 v = *(const float4*)&frw[((size_t)bb * 1024 + e0 + er + i * 16) * 1024 + d0 + dr];
      *(float4*)&T[er + i * 16][dr] = v;
    }
  }
  __syncthreads();
  const int d = tid >> 2, eo = (tid & 3) * 16;
  ushort hs[16], ls[16];
#pragma unroll
  for (int j = 0; j < 16; ++j) split2(T[eo + j][d], hs[j], ls[j]);
  const size_t nbase = ((size_t)bb * 1024 + d0 + d) * 1024 + e0 + eo;
  bf16x8 v0, v1;
#pragma unroll
  for (int j = 0; j < 8; ++j) { v0[j] = (short)hs[j]; v1[j] = (short)hs[j + 8]; }
  *(bf16x8*)&frT[nbase] = v0; *(bf16x8*)&frT[nbase + 8] = v1;
#pragma unroll
  for (int j = 0; j < 8; ++j) { v0[j] = (short)ls[j]; v1[j] = (short)ls[j + 8]; }
  *(bf16x8*)&frT[(4u << 20) + nbase] = v0; *(bf16x8*)&frT[(4u << 20) + nbase + 8] = v1;
}

// ---------------------------------------------------------------------------
// Elementwise split2 of ffw (one-time; kills the 32x re-split in gemm_ff).
// ---------------------------------------------------------------------------
__global__ __launch_bounds__(256) void split_ffw(
    const float* __restrict__ ffw, ushort* __restrict__ fh, ushort* __restrict__ fl)
{
  int i = blockIdx.x * 256 + threadIdx.x;
  float4 v = ((const float4*)ffw)[i];
  ushort4 h, l;
  split2(v.x, h.x, l.x); split2(v.y, h.y, l.y);
  split2(v.z, h.z, l.z); split2(v.w, h.w, l.w);
  ((ushort4*)fh)[i] = h; ((ushort4*)fl)[i] = l;
}

// ---------------------------------------------------------------------------
// q/k projection MFMA: fragment-major LDS, truncation split3 in A-staging.
// ---------------------------------------------------------------------------
__global__ __launch_bounds__(256) void proj_qk_mfma(
    const float* __restrict__ x, const ushort* __restrict__ wT,
    float* __restrict__ qf, ushort* __restrict__ kh,
    ushort* __restrict__ km, ushort* __restrict__ kl)
{
  const int zi = blockIdx.z;
  const ushort* wt = wT + (size_t)zi * 3 * (1u << 20);
  const int m0 = blockIdx.x * 128, n0 = blockIdx.y * 128;
  __shared__ ushort As[3 * 4096];
  __shared__ ushort Bs[3 * 4096];
  const int tid = threadIdx.x;
  const int wave = tid >> 6, lane = tid & 63, l15 = lane & 15, quad = lane >> 4;
  const int wm = wave >> 1, wn = wave & 1;
  const int sr = tid >> 1, q0 = (tid & 1) * 2;
  const int wb0 = FRAG_IDX(sr >> 4, q0, sr & 15);
  const int wb1 = FRAG_IDX(sr >> 4, q0 + 1, sr & 15);
  f32x4 acc[4][4] = {};
  for (int k0 = 0; k0 < 1024; k0 += 32) {
    __syncthreads();
    {
      const float* ap = x + (size_t)(m0 + sr) * 1024 + k0 + q0 * 8;
      float xs[16];
      *(float4*)&xs[0]  = *(const float4*)(ap);
      *(float4*)&xs[4]  = *(const float4*)(ap + 4);
      *(float4*)&xs[8]  = *(const float4*)(ap + 8);
      *(float4*)&xs[12] = *(const float4*)(ap + 12);
      bf16x8 h0, h1, m0v, m1v, l0, l1;
#pragma unroll
      for (int j = 0; j < 8; ++j) {
        ushort hu, mu, lu;
        split3t(xs[j], hu, mu, lu);
        h0[j] = (short)hu; m0v[j] = (short)mu; l0[j] = (short)lu;
        split3t(xs[j + 8], hu, mu, lu);
        h1[j] = (short)hu; m1v[j] = (short)mu; l1[j] = (short)lu;
      }
      *(bf16x8*)&As[wb0] = h0;          *(bf16x8*)&As[wb1] = h1;
      *(bf16x8*)&As[4096 + wb0] = m0v;  *(bf16x8*)&As[4096 + wb1] = m1v;
      *(bf16x8*)&As[8192 + wb0] = l0;   *(bf16x8*)&As[8192 + wb1] = l1;
#pragma unroll
      for (int s = 0; s < 3; ++s) {
        const ushort* bp = wt + ((size_t)s << 20) + (size_t)(n0 + sr) * 1024 + k0 + q0 * 8;
        *(bf16x8*)&Bs[s * 4096 + wb0] = *(const bf16x8*)(bp);
        *(bf16x8*)&Bs[s * 4096 + wb1] = *(const bf16x8*)(bp + 8);
      }
    }
    __syncthreads();
    bf16x8 af[4][3];
#pragma unroll
    for (int tm = 0; tm < 4; ++tm)
#pragma unroll
      for (int s = 0; s < 3; ++s)
        af[tm][s] = *(const bf16x8*)&As[s * 4096 + FRAG_IDX(wm * 4 + tm, quad, l15)];
#pragma unroll
    for (int tn = 0; tn < 4; ++tn) {
      const int bi = FRAG_IDX(wn * 4 + tn, quad, l15);
      bf16x8 b0 = *(const bf16x8*)&Bs[bi];
      bf16x8 b1 = *(const bf16x8*)&Bs[4096 + bi];
      bf16x8 b2 = *(const bf16x8*)&Bs[8192 + bi];
#pragma unroll
      for (int tm = 0; tm < 4; ++tm) {
        f32x4 a = acc[tm][tn];
        a = __builtin_amdgcn_mfma_f32_16x16x32_bf16(af[tm][0], b0, a, 0, 0, 0);
        a = __builtin_amdgcn_mfma_f32_16x16x32_bf16(af[tm][0], b1, a, 0, 0, 0);
        a = __builtin_amdgcn_mfma_f32_16x16x32_bf16(af[tm][1], b0, a, 0, 0, 0);
        a = __builtin_amdgcn_mfma_f32_16x16x32_bf16(af[tm][0], b2, a, 0, 0, 0);
        a = __builtin_amdgcn_mfma_f32_16x16x32_bf16(af[tm][1], b1, a, 0, 0, 0);
        a = __builtin_amdgcn_mfma_f32_16x16x32_bf16(af[tm][2], b0, a, 0, 0, 0);
        acc[tm][tn] = a;
      }
    }
  }
#pragma unroll
  for (int tm = 0; tm < 4; ++tm) {
#pragma unroll
    for (int tn = 0; tn < 4; ++tn) {
#pragma unroll
      for (int r = 0; r < 4; ++r) {
        int m = m0 + wm * 64 + tm * 16 + quad * 4 + r;
        int n = n0 + wn * 64 + tn * 16 + l15;
        int b = m >> 10, t = m & 1023, h = n >> 6, f = n & 63;
        size_t idx = (((size_t)(b * 16 + h)) * 1024 + t) * 64 + f;
        if (zi == 0) {
          qf[idx] = acc[tm][tn][r];
        } else {
          ushort hu, mu, lu;
          split3(acc[tm][tn][r], hu, mu, lu);
          kh[idx] = hu; km[idx] = mu; kl[idx] = lu;
        }
      }
    }
  }
}

// ---------------------------------------------------------------------------
// v projection MFMA: fragment-major LDS.
// ---------------------------------------------------------------------------
__global__ __launch_bounds__(256) void proj_v_mfma(
    const float* __restrict__ x, const ushort* __restrict__ wT,
    ushort* __restrict__ vt)
{
  const ushort* wt = wT + (size_t)6 * (1u << 20);
  const int m0 = blockIdx.x * 128, n0 = blockIdx.y * 128;
  __shared__ ushort As[4096];
  __shared__ ushort Bs[4096];
  const int tid = threadIdx.x;
  const int wave = tid >> 6, lane = tid & 63, l15 = lane & 15, quad = lane >> 4;
  const int wm = wave >> 1, wn = wave & 1;
  const int sr = tid >> 1, q0 = (tid & 1) * 2;
  const int wb0 = FRAG_IDX(sr >> 4, q0, sr & 15);
  const int wb1 = FRAG_IDX(sr >> 4, q0 + 1, sr & 15);
  f32x4 acc[4][4] = {};
  for (int k0 = 0; k0 < 1024; k0 += 32) {
    __syncthreads();
    {
      const float* ap = x + (size_t)(m0 + sr) * 1024 + k0 + q0 * 8;
      float xs[16];
      *(float4*)&xs[0]  = *(const float4*)(ap);
      *(float4*)&xs[4]  = *(const float4*)(ap + 4);
      *(float4*)&xs[8]  = *(const float4*)(ap + 8);
      *(float4*)&xs[12] = *(const float4*)(ap + 12);
      bf16x8 h0, h1;
#pragma unroll
      for (int j = 0; j < 8; ++j) {
        h0[j] = (short)f2bf(xs[j]);
        h1[j] = (short)f2bf(xs[j + 8]);
      }
      *(bf16x8*)&As[wb0] = h0; *(bf16x8*)&As[wb1] = h1;
      const ushort* bp = wt + (size_t)(n0 + sr) * 1024 + k0 + q0 * 8;
      *(bf16x8*)&Bs[wb0] = *(const bf16x8*)(bp);
      *(bf16x8*)&Bs[wb1] = *(const bf16x8*)(bp + 8);
    }
    __syncthreads();
    bf16x8 af[4];
#pragma unroll
    for (int tm = 0; tm < 4; ++tm)
      af[tm] = *(const bf16x8*)&As[FRAG_IDX(wm * 4 + tm, quad, l15)];
#pragma unroll
    for (int tn = 0; tn < 4; ++tn) {
      bf16x8 b0 = *(const bf16x8*)&Bs[FRAG_IDX(wn * 4 + tn, quad, l15)];
#pragma unroll
      for (int tm = 0; tm < 4; ++tm)
        acc[tm][tn] = __builtin_amdgcn_mfma_f32_16x16x32_bf16(af[tm], b0, acc[tm][tn], 0, 0, 0);
    }
  }
#pragma unroll
  for (int tm = 0; tm < 4; ++tm) {
#pragma unroll
    for (int tn = 0; tn < 4; ++tn) {
#pragma unroll
      for (int r = 0; r < 4; ++r) {
        int m = m0 + wm * 64 + tm * 16 + quad * 4 + r;
        int n = n0 + wn * 64 + tn * 16 + l15;
        int b = m >> 10, t = m & 1023, h = n >> 6, f = n & 63;
        vt[(((size_t)(b * 16 + h)) * 64 + f) * 1024 + t] = f2bf(acc[tm][tn][r]);
      }
    }
  }
}

// ---------------------------------------------------------------------------
// Flash attention (round-8 structure). Epilogue now writes z pre-split2
// (zh/zl bf16) so gemm_fr's A-staging is a pure copy. Same split2 values as
// gemm_fr previously computed -> bit-identical MFMA inputs.
// ---------------------------------------------------------------------------
__global__ __launch_bounds__(512) void attn_mfma(
    const float* __restrict__ qf, const ushort* __restrict__ kh,
    const ushort* __restrict__ km, const ushort* __restrict__ kl,
    const ushort* __restrict__ vt, ushort* __restrict__ zh, ushort* __restrict__ zl)
{
  __shared__ ushort Ks[3][64][68];
  __shared__ ushort Vs[64][68];
  __shared__ ushort Pl[8][16][68];

  const int tid = threadIdx.x;
  const int wave = tid >> 6, lane = tid & 63;
  const int l15 = lane & 15, quad = lane >> 4;
  const int bh = blockIdx.y;
  const int qbase = blockIdx.x * 128;

  bf16x8 aqh[2], aqm[2], aql[2];
  {
    const int qrow = qbase + wave * 16 + l15;
    const float* qp = qf + ((size_t)bh * Tc + qrow) * Fc;
#pragma unroll
    for (int ks = 0; ks < 2; ++ks) {
      int f0 = ks * 32 + quad * 8;
      float4 x0 = *(const float4*)(qp + f0);
      float4 x1 = *(const float4*)(qp + f0 + 4);
      float xs[8] = {x0.x, x0.y, x0.z, x0.w, x1.x, x1.y, x1.z, x1.w};
#pragma unroll
      for (int j = 0; j < 8; ++j) {
        ushort hu, mu, lu;
        split3(xs[j], hu, mu, lu);
        aqh[ks][j] = (short)hu; aqm[ks][j] = (short)mu; aql[ks][j] = (short)lu;
      }
    }
  }

  f32x4 o[4] = {{0,0,0,0},{0,0,0,0},{0,0,0,0},{0,0,0,0}};
  float m_run[4], l_run[4];
#pragma unroll
  for (int r = 0; r < 4; ++r) { m_run[r] = -1e30f; l_run[r] = 0.f; }

  const int srow = tid >> 3, sc8 = tid & 7;
  const size_t kbase = (size_t)bh * Tc * Fc;
  const size_t vbase = (size_t)bh * Fc * Tc;
  const ushort* kp0 = kh + kbase + (size_t)srow * Fc + sc8 * 8;
  const ushort* kp1 = km + kbase + (size_t)srow * Fc + sc8 * 8;
  const ushort* kp2 = kl + kbase + (size_t)srow * Fc + sc8 * 8;
  const ushort* vp  = vt + vbase + (size_t)srow * Tc + sc8 * 8;

  for (int kt = 0; kt < Tc; kt += 64) {
    __syncthreads();
    {
      const size_t ko = (size_t)kt * Fc;
      *(bf16x8*)&Ks[0][srow][sc8 * 8] = *(const bf16x8*)(kp0 + ko);
      *(bf16x8*)&Ks[1][srow][sc8 * 8] = *(const bf16x8*)(kp1 + ko);
      *(bf16x8*)&Ks[2][srow][sc8 * 8] = *(const bf16x8*)(kp2 + ko);
      *(bf16x8*)&Vs[srow][sc8 * 8]    = *(const bf16x8*)(vp + kt);
    }
    __syncthreads();

    f32x4 sacc[4] = {{0,0,0,0},{0,0,0,0},{0,0,0,0},{0,0,0,0}};
#pragma unroll
    for (int nt = 0; nt < 4; ++nt) {
      int key = nt * 16 + l15;
#pragma unroll
      for (int ks = 0; ks < 2; ++ks) {
        int f0 = ks * 32 + quad * 8;
        bf16x8 bh_ = *(const bf16x8*)&Ks[0][key][f0];
        bf16x8 bm_ = *(const bf16x8*)&Ks[1][key][f0];
        bf16x8 bl_ = *(const bf16x8*)&Ks[2][key][f0];
        sacc[nt] = __builtin_amdgcn_mfma_f32_16x16x32_bf16(aqh[ks], bh_, sacc[nt], 0, 0, 0);
        sacc[nt] = __builtin_amdgcn_mfma_f32_16x16x32_bf16(aqh[ks], bm_, sacc[nt], 0, 0, 0);
        sacc[nt] = __builtin_amdgcn_mfma_f32_16x16x32_bf16(aqm[ks], bh_, sacc[nt], 0, 0, 0);
        sacc[nt] = __builtin_amdgcn_mfma_f32_16x16x32_bf16(aqh[ks], bl_, sacc[nt], 0, 0, 0);
        sacc[nt] = __builtin_amdgcn_mfma_f32_16x16x32_bf16(aqm[ks], bm_, sacc[nt], 0, 0, 0);
        sacc[nt] = __builtin_amdgcn_mfma_f32_16x16x32_bf16(aql[ks], bh_, sacc[nt], 0, 0, 0);
      }
    }

    const int rowg0 = qbase + wave * 16 + quad * 4;
    float mx[4];
#pragma unroll
    for (int r = 0; r < 4; ++r) mx[r] = -1e30f;
#pragma unroll
    for (int nt = 0; nt < 4; ++nt) {
      int key = kt + nt * 16 + l15;
#pragma unroll
      for (int r = 0; r < 4; ++r) {
        float s = sacc[nt][r];
        if (key > rowg0 + r) s *= -1.0e9f + 1.0f;
        s *= 0.125f;
        sacc[nt][r] = s;
        mx[r] = fmaxf(mx[r], s);
      }
    }
#pragma unroll
    for (int r = 0; r < 4; ++r)
#pragma unroll
      for (int d = 1; d < 16; d <<= 1) mx[r] = fmaxf(mx[r], __shfl_xor(mx[r], d));

    float corr[4], ps[4];
#pragma unroll
    for (int r = 0; r < 4; ++r) {
      float m2 = fmaxf(m_run[r], mx[r]);
      corr[r] = __expf(m_run[r] - m2);
      m_run[r] = m2;
      ps[r] = 0.f;
    }
#pragma unroll
    for (int nt = 0; nt < 4; ++nt) {
#pragma unroll
      for (int r = 0; r < 4; ++r) {
        float p = __expf(sacc[nt][r] - m_run[r]);
        ps[r] += p;
        Pl[wave][quad * 4 + r][nt * 16 + l15] = f2bf(p);
      }
    }
#pragma unroll
    for (int r = 0; r < 4; ++r) {
#pragma unroll
      for (int d = 1; d < 16; d <<= 1) ps[r] += __shfl_xor(ps[r], d);
      l_run[r] = l_run[r] * corr[r] + ps[r];
#pragma unroll
      for (int ft = 0; ft < 4; ++ft) o[ft][r] *= corr[r];
    }

#pragma unroll
    for (int ks2 = 0; ks2 < 2; ++ks2) {
      bf16x8 pa = *(const bf16x8*)&Pl[wave][l15][ks2 * 32 + quad * 8];
#pragma unroll
      for (int ft = 0; ft < 4; ++ft) {
        bf16x8 vb = *(const bf16x8*)&Vs[ft * 16 + l15][ks2 * 32 + quad * 8];
        o[ft] = __builtin_amdgcn_mfma_f32_16x16x32_bf16(pa, vb, o[ft], 0, 0, 0);
      }
    }
  }

  const int b = bh >> 4, h = bh & 15;
#pragma unroll
  for (int r = 0; r < 4; ++r) {
    float inv = 1.f / l_run[r];
    int row = qbase + wave * 16 + quad * 4 + r;
    size_t base = ((size_t)(b * Tc + row)) * Ec + h * Fc;
#pragma unroll
    for (int ft = 0; ft < 4; ++ft) {
      ushort hu, lu;
      split2(o[ft][r] * inv, hu, lu);
      zh[base + ft * 16 + l15] = hu;
      zl[base + ft * 16 + l15] = lu;
    }
  }
}

// ---------------------------------------------------------------------------
// fr GEMM: pure-copy staging (z pre-split by attn, frT pre-split), fragment-
// major LDS. Epilogue: s1 = x + acc, LN1 partials.
// ---------------------------------------------------------------------------
__global__ __launch_bounds__(256) void gemm_fr_mfma(
    const ushort* __restrict__ zh, const ushort* __restrict__ zl,
    const ushort* __restrict__ frT, const float* __restrict__ x,
    float* __restrict__ s1, float2* __restrict__ part)
{
  const int bb = blockIdx.z;
  const int m0 = blockIdx.x * 128, n0 = blockIdx.y * 128;
  __shared__ ushort Ah[4096], Al[4096], Bh[4096], Bl[4096];
  __shared__ float2 red[256];
  const int tid = threadIdx.x;
  const int wave = tid >> 6, lane = tid & 63, l15 = lane & 15, quad = lane >> 4;
  const int wm = wave >> 1, wn = wave & 1;
  const int sr = tid >> 1, q0 = (tid & 1) * 2;
  const int wb0 = FRAG_IDX(sr >> 4, q0, sr & 15);
  const int wb1 = FRAG_IDX(sr >> 4, q0 + 1, sr & 15);
  f32x4 acc[4][4] = {};
  const size_t abase = ((size_t)bb * 1024 + m0 + sr) * 1024 + q0 * 8;
  const size_t bbase = ((size_t)bb * 1024 + n0 + sr) * 1024 + q0 * 8;
  const ushort* blp = frT + (4u << 20);
  for (int k0 = 0; k0 < 1024; k0 += 32) {
    __syncthreads();
    {
      *(bf16x8*)&Ah[wb0] = *(const bf16x8*)(zh + abase + k0);
      *(bf16x8*)&Ah[wb1] = *(const bf16x8*)(zh + abase + k0 + 8);
      *(bf16x8*)&Al[wb0] = *(const bf16x8*)(zl + abase + k0);
      *(bf16x8*)&Al[wb1] = *(const bf16x8*)(zl + abase + k0 + 8);
      *(bf16x8*)&Bh[wb0] = *(const bf16x8*)(frT + bbase + k0);
      *(bf16x8*)&Bh[wb1] = *(const bf16x8*)(frT + bbase + k0 + 8);
      *(bf16x8*)&Bl[wb0] = *(const bf16x8*)(blp + bbase + k0);
      *(bf16x8*)&Bl[wb1] = *(const bf16x8*)(blp + bbase + k0 + 8);
    }
    __syncthreads();
    bf16x8 ah[4], al[4];
#pragma unroll
    for (int tm = 0; tm < 4; ++tm) {
      ah[tm] = *(const bf16x8*)&Ah[FRAG_IDX(wm * 4 + tm, quad, l15)];
      al[tm] = *(const bf16x8*)&Al[FRAG_IDX(wm * 4 + tm, quad, l15)];
    }
#pragma unroll
    for (int tn = 0; tn < 4; ++tn) {
      const int bi = FRAG_IDX(wn * 4 + tn, quad, l15);
      bf16x8 b0 = *(const bf16x8*)&Bh[bi];
      bf16x8 b1 = *(const bf16x8*)&Bl[bi];
#pragma unroll
      for (int tm = 0; tm < 4; ++tm) {
        f32x4 a = acc[tm][tn];
        a = __builtin_amdgcn_mfma_f32_16x16x32_bf16(ah[tm], b0, a, 0, 0, 0);
        a = __builtin_amdgcn_mfma_f32_16x16x32_bf16(ah[tm], b1, a, 0, 0, 0);
        a = __builtin_amdgcn_mfma_f32_16x16x32_bf16(al[tm], b0, a, 0, 0, 0);
        acc[tm][tn] = a;
      }
    }
  }
  float sum = 0.f, sq = 0.f;
#pragma unroll
  for (int tm = 0; tm < 4; ++tm) {
#pragma unroll
    for (int tn = 0; tn < 4; ++tn) {
#pragma unroll
      for (int r = 0; r < 4; ++r) {
        int m = m0 + wm * 64 + tm * 16 + quad * 4 + r;
        int n = n0 + wn * 64 + tn * 16 + l15;
        size_t idx = ((size_t)bb * 1024 + m) * 1024 + n;
        float o = x[idx] + acc[tm][tn][r];
        s1[idx] = o;
        sum += o; sq += o * o;
      }
    }
  }
  red[tid] = make_float2(sum, sq);
  __syncthreads();
  for (int s = 128; s > 0; s >>= 1) {
    if (tid < s) { red[tid].x += red[tid + s].x; red[tid].y += red[tid + s].y; }
    __syncthreads();
  }
  if (tid == 0) part[(bb * 8 + blockIdx.x) * 8 + blockIdx.y] = red[0];
}

// ---------------------------------------------------------------------------
// ff GEMM: pure-copy staging (z1 pre-split by ln_norm_split, ffw pre-split),
// fragment-major LDS. Residual reconstructed as bf2f(h)+bf2f(l) (err ~1e-5).
// ---------------------------------------------------------------------------
__global__ __launch_bounds__(256) void gemm_ff_mfma(
    const ushort* __restrict__ z1h, const ushort* __restrict__ z1l,
    const ushort* __restrict__ fwh, const ushort* __restrict__ fwl,
    const float* __restrict__ ffb, float* __restrict__ s2,
    float2* __restrict__ part)
{
  const int m0 = blockIdx.x * 128, n0 = blockIdx.y * 128;
  __shared__ ushort Ah[4096], Al[4096], Bh[4096], Bl[4096];
  __shared__ float2 red[256];
  const int tid = threadIdx.x;
  const int wave = tid >> 6, lane = tid & 63, l15 = lane & 15, quad = lane >> 4;
  const int wm = wave >> 1, wn = wave & 1;
  const int sr = tid >> 1, q0 = (tid & 1) * 2;
  const int wb0 = FRAG_IDX(sr >> 4, q0, sr & 15);
  const int wb1 = FRAG_IDX(sr >> 4, q0 + 1, sr & 15);
  f32x4 acc[4][4] = {};
  const size_t abase = (size_t)(m0 + sr) * 1024 + q0 * 8;
  const size_t bbase = (size_t)(n0 + sr) * 1024 + q0 * 8;
  for (int k0 = 0; k0 < 1024; k0 += 32) {
    __syncthreads();
    {
      *(bf16x8*)&Ah[wb0] = *(const bf16x8*)(z1h + abase + k0);
      *(bf16x8*)&Ah[wb1] = *(const bf16x8*)(z1h + abase + k0 + 8);
      *(bf16x8*)&Al[wb0] = *(const bf16x8*)(z1l + abase + k0);
      *(bf16x8*)&Al[wb1] = *(const bf16x8*)(z1l + abase + k0 + 8);
      *(bf16x8*)&Bh[wb0] = *(const bf16x8*)(fwh + bbase + k0);
      *(bf16x8*)&Bh[wb1] = *(const bf16x8*)(fwh + bbase + k0 + 8);
      *(bf16x8*)&Bl[wb0] = *(const bf16x8*)(fwl + bbase + k0);
      *(bf16x8*)&Bl[wb1] = *(const bf16x8*)(fwl + bbase + k0 + 8);
    }
    __syncthreads();
    bf16x8 ah[4], al[4];
#pragma unroll
    for (int tm = 0; tm < 4; ++tm) {
      ah[tm] = *(const bf16x8*)&Ah[FRAG_IDX(wm * 4 + tm, quad, l15)];
      al[tm] = *(const bf16x8*)&Al[FRAG_IDX(wm * 4 + tm, quad, l15)];
    }
#pragma unroll
    for (int tn = 0; tn < 4; ++tn) {
      const int bi = FRAG_IDX(wn * 4 + tn, quad, l15);
      bf16x8 b0 = *(const bf16x8*)&Bh[bi];
      bf16x8 b1 = *(const bf16x8*)&Bl[bi];
#pragma unroll
      for (int tm = 0; tm < 4; ++tm) {
        f32x4 a = acc[tm][tn];
        a = __builtin_amdgcn_mfma_f32_16x16x32_bf16(ah[tm], b0, a, 0, 0, 0);
        a = __builtin_amdgcn_mfma_f32_16x16x32_bf16(ah[tm], b1, a, 0, 0, 0);
        a = __builtin_amdgcn_mfma_f32_16x16x32_bf16(al[tm], b0, a, 0, 0, 0);
        acc[tm][tn] = a;
      }
    }
  }
  float sum = 0.f, sq = 0.f;
#pragma unroll
  for (int tm = 0; tm < 4; ++tm) {
#pragma unroll
    for (int tn = 0; tn < 4; ++tn) {
#pragma unroll
      for (int r = 0; r < 4; ++r) {
        int m = m0 + wm * 64 + tm * 16 + quad * 4 + r;
        int n = n0 + wn * 64 + tn * 16 + l15;
        size_t idx = (size_t)m * 1024 + n;
        float z1v = bf2f(z1h[idx]) + bf2f(z1l[idx]);
        float o = z1v + fmaxf(acc[tm][tn][r] + ffb[n], 0.f);
        s2[idx] = o;
        sum += o; sq += o * o;
      }
    }
  }
  red[tid] = make_float2(sum, sq);
  __syncthreads();
  for (int s = 128; s > 0; s >>= 1) {
    if (tid < s) { red[tid].x += red[tid + s].x; red[tid].y += red[tid + s].y; }
    __syncthreads();
  }
  if (tid == 0) part[blockIdx.x * 8 + blockIdx.y] = red[0];
}

__global__ __launch_bounds__(256) void ln_stats(
    const float2* __restrict__ part, float2* __restrict__ stats, int npart)
{
  __shared__ double sd[256], sq[256];
  const int tid = threadIdx.x;
  float2 p = (tid < npart) ? part[blockIdx.x * npart + tid] : make_float2(0.f, 0.f);
  sd[tid] = (double)p.x; sq[tid] = (double)p.y;
  __syncthreads();
  for (int s = 128; s > 0; s >>= 1) {
    if (tid < s) { sd[tid] += sd[tid + s]; sq[tid] += sq[tid + s]; }
    __syncthreads();
  }
  if (tid == 0) {
    const double n = (double)Tc * Ec;
    double mean = sd[0] / n;
    double var = sq[0] / n - mean * mean;
    if (var < 0.0) var = 0.0;
    double rs = 1.0 / sqrt(var + 1e-5);
    stats[blockIdx.x] = make_float2((float)mean, (float)rs);
  }
}

// ln_norm writing split2 bf16 pair (for gemm_ff A-operand + residual).
__global__ __launch_bounds__(256) void ln_norm_split(
    const float* __restrict__ s, const float2* __restrict__ stats,
    const float* __restrict__ w, const float* __restrict__ bias,
    ushort* __restrict__ oh, ushort* __restrict__ ol)
{
  int i = blockIdx.x * 256 + threadIdx.x;
  if (i >= (Bc * Tc * Ec) / 4) return;
  int b = i >> 18;
  int te4 = i & ((1 << 18) - 1);
  float2 st = stats[b];
  float4 sv = ((const float4*)s)[i];
  float4 wv = ((const float4*)w)[te4];
  float4 bv = ((const float4*)bias)[te4];
  float4 o;
  o.x = (sv.x - st.x) * st.y * wv.x + bv.x;
  o.y = (sv.y - st.x) * st.y * wv.y + bv.y;
  o.z = (sv.z - st.x) * st.y * wv.z + bv.z;
  o.w = (sv.w - st.x) * st.y * wv.w + bv.w;
  ushort4 h, l;
  split2(o.x, h.x, l.x); split2(o.y, h.y, l.y);
  split2(o.z, h.z, l.z); split2(o.w, h.w, l.w);
  ((ushort4*)oh)[i] = h; ((ushort4*)ol)[i] = l;
}

__global__ __launch_bounds__(256) void ln_norm(
    const float* __restrict__ s, const float2* __restrict__ stats,
    const float* __restrict__ w, const float* __restrict__ bias,
    float* __restrict__ out)
{
  int i = blockIdx.x * 256 + threadIdx.x;
  if (i >= (Bc * Tc * Ec) / 4) return;
  int b = i >> 18;
  int te4 = i & ((1 << 18) - 1);
  float2 st = stats[b];
  float4 sv = ((const float4*)s)[i];
  float4 wv = ((const float4*)w)[te4];
  float4 bv = ((const float4*)bias)[te4];
  float4 o;
  o.x = (sv.x - st.x) * st.y * wv.x + bv.x;
  o.y = (sv.y - st.x) * st.y * wv.y + bv.y;
  o.z = (sv.z - st.x) * st.y * wv.z + bv.z;
  o.w = (sv.w - st.x) * st.y * wv.w + bv.w;
  ((float4*)out)[i] = o;
}

// ---------------------------------------------------------------------------
extern "C" void kernel_launch(void* const* d_in, const int* in_sizes, int n_in,
                              void* d_out, int out_size, void* d_ws, size_t ws_size,
                              hipStream_t stream)
{
  const float* x    = (const float*)d_in[0];
  const float* qw   = (const float*)d_in[1];
  const float* kw   = (const float*)d_in[2];
  const float* vw   = (const float*)d_in[3];
  const float* frw  = (const float*)d_in[4];
  const float* ffw  = (const float*)d_in[5];
  const float* ffb  = (const float*)d_in[6];
  const float* ln1w = (const float*)d_in[7];
  const float* ln1b = (const float*)d_in[8];
  const float* ln2w = (const float*)d_in[9];
  const float* ln2b = (const float*)d_in[10];
  float* out = (float*)d_out;
  char* W = (char*)d_ws;

  const size_t MB = 1ull << 20;
  // Footprint: 64 MB + 16.4 KB (proven).
  // Phase liveness:
  //  proj:  qf 0-16 | kh/km/kl 16-40 | vt 40-48 | wT 48-62
  //  attn:  reads qf,k*,vt; writes zh 48-56, zl 56-64 (wT dead)
  //  fr:    reads zh/zl + frT 16-32 (kh/km dead) + x; writes s1 0-16 (qf dead)
  //  ln1:   s1 -> z1h 16-24, z1l 24-32 (frT dead)
  //  ff:    reads z1h/z1l + ffw splits 48-52 (zh dead) ; writes s2 32-48
  //  ln2:   s2 -> out
  float*  qf  = (float*)(W);
  ushort* kh  = (ushort*)(W + 16 * MB);
  ushort* km  = (ushort*)(W + 24 * MB);
  ushort* kl  = (ushort*)(W + 32 * MB);
  ushort* vt  = (ushort*)(W + 40 * MB);
  ushort* wT  = (ushort*)(W + 48 * MB);
  ushort* zh  = (ushort*)(W + 48 * MB);
  ushort* zl  = (ushort*)(W + 56 * MB);
  ushort* frT = (ushort*)(W + 16 * MB);
  float*  s1  = (float*)(W);
  ushort* z1h = (ushort*)(W + 16 * MB);
  ushort* z1l = (ushort*)(W + 24 * MB);
  ushort* fwh = (ushort*)(W + 48 * MB);
  ushort* fwl = (ushort*)(W + 50 * MB);
  float*  s2  = (float*)(W + 32 * MB);
  float2* part1  = (float2*)(W + 64 * MB);
  float2* part2  = part1 + 1024;
  float2* stats1 = part2 + 1024;
  float2* stats2 = stats1 + 4;

  transp_w<<<dim3(16, 16, 3), 256, 0, stream>>>(qw, kw, vw, wT);
  proj_qk_mfma<<<dim3(32, 8, 2), 256, 0, stream>>>(x, wT, qf, kh, km, kl);
  proj_v_mfma<<<dim3(32, 8), 256, 0, stream>>>(x, wT, vt);
  attn_mfma<<<dim3(8, 64), 512, 0, stream>>>(qf, kh, km, kl, vt, zh, zl);
  transp_frw<<<dim3(16, 16, 4), 256, 0, stream>>>(frw, frT);
  gemm_fr_mfma<<<dim3(8, 8, 4), 256, 0, stream>>>(zh, zl, frT, x, s1, part1);
  ln_stats<<<dim3(4), 256, 0, stream>>>(part1, stats1, 64);
  ln_norm_split<<<dim3(4096), 256, 0, stream>>>(s1, stats1, ln1w, ln1b, z1h, z1l);
  split_ffw<<<dim3(1024), 256, 0, stream>>>(ffw, fwh, fwl);
  gemm_ff_mfma<<<dim3(32, 8), 256, 0, stream>>>(z1h, z1l, fwh, fwl, ffb, s2, part2);
  ln_stats<<<dim3(4), 256, 0, stream>>>(part2, stats2, 64);
  ln_norm<<<dim3(4096), 256, 0, stream>>>(s2, stats2, ln2w, ln2b, out);
}

// Round 10
// 429.038 us; speedup vs baseline: 1.1994x; 1.0407x over previous
//
#include <hip/hip_runtime.h>
#include <math.h>

constexpr int Bc = 4, Tc = 1024, Ec = 1024, Hc = 16, Fc = 64;

typedef __attribute__((ext_vector_type(8))) short bf16x8;
typedef __attribute__((ext_vector_type(4))) float f32x4;

__device__ __forceinline__ ushort f2bf(float x) {
  union { float f; unsigned u; } v; v.f = x;
  unsigned r = v.u + 0x7fffu + ((v.u >> 16) & 1u);
  return (ushort)(r >> 16);
}
__device__ __forceinline__ float bf2f(ushort h) {
  union { float f; unsigned u; } v; v.u = ((unsigned)h) << 16; return v.f;
}
__device__ __forceinline__ void split3(float x, ushort& h, ushort& m, ushort& l) {
  h = f2bf(x);
  float r1 = x - bf2f(h);
  m = f2bf(r1);
  float r2 = r1 - bf2f(m);
  l = f2bf(r2);
}
__device__ __forceinline__ void split2(float x, ushort& h, ushort& l) {
  h = f2bf(x);
  l = f2bf(x - bf2f(h));
}
// Truncation split3 (~8 VALU ops): one-sided residual < 2^-22 rel.
__device__ __forceinline__ void split3t(float x, ushort& h, ushort& m, ushort& l) {
  union { float f; unsigned u; } v; v.f = x;
  h = (ushort)(v.u >> 16);
  union { float f; unsigned u; } hf; hf.u = v.u & 0xffff0000u;
  float r1 = x - hf.f;
  union { float f; unsigned u; } v1; v1.f = r1;
  m = (ushort)(v1.u >> 16);
  union { float f; unsigned u; } mf; mf.u = v1.u & 0xffff0000u;
  float r2 = r1 - mf.f;
  union { float f; unsigned u; } v2; v2.f = r2;
  l = (ushort)(v2.u >> 16);
}

// Fragment-major LDS cell: [tile(0..7)][quad(0..3)][lane(0..15)][8 ushorts]
#define FRAG_IDX(tile, quad, l) (((((tile) * 4) + (quad)) * 16 + (l)) * 8)

// ---------------------------------------------------------------------------
// Pre-transpose + split projection weights (unchanged).
// ---------------------------------------------------------------------------
__global__ __launch_bounds__(256) void transp_w(
    const float* __restrict__ qw, const float* __restrict__ kw,
    const float* __restrict__ vw, ushort* __restrict__ wT)
{
  const int zi = blockIdx.z;
  const float* src = (zi == 0) ? qw : (zi == 1) ? kw : vw;
  ushort* dst = wT + (size_t)(zi * 3) * (1u << 20);
  const int ns = (zi == 2) ? 1 : 3;
  const int h = blockIdx.y, e0 = blockIdx.x * 64;
  __shared__ float T[64][68];
  const int tid = threadIdx.x;
  {
    const int er = tid >> 4, fr = (tid & 15) * 4;
#pragma unroll
    for (int i = 0; i < 4; ++i) {
      const float4 v = *(const float4*)&src[((size_t)(h * 1024 + e0 + er + i * 16)) * 64 + fr];
      *(float4*)&T[er + i * 16][fr] = v;
    }
  }
  __syncthreads();
  const int f = tid >> 2, eo = (tid & 3) * 16;
  ushort hs[16], ms[16], ls[16];
#pragma unroll
  for (int j = 0; j < 16; ++j) split3(T[eo + j][f], hs[j], ms[j], ls[j]);
  const size_t nbase = (size_t)(h * 64 + f) * 1024 + e0 + eo;
  bf16x8 v0, v1;
#pragma unroll
  for (int j = 0; j < 8; ++j) { v0[j] = (short)hs[j]; v1[j] = (short)hs[j + 8]; }
  *(bf16x8*)&dst[nbase] = v0; *(bf16x8*)&dst[nbase + 8] = v1;
  if (ns == 3) {
#pragma unroll
    for (int j = 0; j < 8; ++j) { v0[j] = (short)ms[j]; v1[j] = (short)ms[j + 8]; }
    *(bf16x8*)&dst[(1u << 20) + nbase] = v0; *(bf16x8*)&dst[(1u << 20) + nbase + 8] = v1;
#pragma unroll
    for (int j = 0; j < 8; ++j) { v0[j] = (short)ls[j]; v1[j] = (short)ls[j + 8]; }
    *(bf16x8*)&dst[(2u << 20) + nbase] = v0; *(bf16x8*)&dst[(2u << 20) + nbase + 8] = v1;
  }
}

// ---------------------------------------------------------------------------
// Pre-transpose + split2 fr weights (unchanged).
// ---------------------------------------------------------------------------
__global__ __launch_bounds__(256) void transp_frw(
    const float* __restrict__ frw, ushort* __restrict__ frT)
{
  const int bb = blockIdx.z;
  const int e0 = blockIdx.x * 64, d0 = blockIdx.y * 64;
  __shared__ float T[64][68];
  const int tid = threadIdx.x;
  {
    const int er = tid >> 4, dr = (tid & 15) * 4;
#pragma unroll
    for (int i = 0; i < 4; ++i) {
      const float4 v = *(const float4*)&frw[((size_t)bb * 1024 + e0 + er + i * 16) * 1024 + d0 + dr];
      *(float4*)&T[er + i * 16][dr] = v;
    }
  }
  __syncthreads();
  const int d = tid >> 2, eo = (tid & 3) * 16;
  ushort hs[16], ls[16];
#pragma unroll
  for (int j = 0; j < 16; ++j) split2(T[eo + j][d], hs[j], ls[j]);
  const size_t nbase = ((size_t)bb * 1024 + d0 + d) * 1024 + e0 + eo;
  bf16x8 v0, v1;
#pragma unroll
  for (int j = 0; j < 8; ++j) { v0[j] = (short)hs[j]; v1[j] = (short)hs[j + 8]; }
  *(bf16x8*)&frT[nbase] = v0; *(bf16x8*)&frT[nbase + 8] = v1;
#pragma unroll
  for (int j = 0; j < 8; ++j) { v0[j] = (short)ls[j]; v1[j] = (short)ls[j + 8]; }
  *(bf16x8*)&frT[(4u << 20) + nbase] = v0; *(bf16x8*)&frT[(4u << 20) + nbase + 8] = v1;
}

// ---------------------------------------------------------------------------
// ALL projections in one launch: zi=0 q (6-product split3), zi=1 k (6-product,
// pre-split epilogue), zi=2 v (1-product bf16, transposed output).
// Grid (32,8,3) = 768 blocks = 3 blocks/CU — v-slice blocks backfill the
// qk-slices' barrier-drain stalls (the m97-structure ~29% idle).
// ---------------------------------------------------------------------------
__global__ __launch_bounds__(256) void proj_all_mfma(
    const float* __restrict__ x, const ushort* __restrict__ wT,
    float* __restrict__ qf, ushort* __restrict__ kh,
    ushort* __restrict__ km, ushort* __restrict__ kl,
    ushort* __restrict__ vt)
{
  const int zi = blockIdx.z;
  const int m0 = blockIdx.x * 128, n0 = blockIdx.y * 128;
  __shared__ ushort As[3 * 4096];
  __shared__ ushort Bs[3 * 4096];
  const int tid = threadIdx.x;
  const int wave = tid >> 6, lane = tid & 63, l15 = lane & 15, quad = lane >> 4;
  const int wm = wave >> 1, wn = wave & 1;
  const int sr = tid >> 1, q0 = (tid & 1) * 2;
  const int wb0 = FRAG_IDX(sr >> 4, q0, sr & 15);
  const int wb1 = FRAG_IDX(sr >> 4, q0 + 1, sr & 15);
  f32x4 acc[4][4] = {};

  if (zi < 2) {
    const ushort* wt = wT + (size_t)zi * 3 * (1u << 20);
    for (int k0 = 0; k0 < 1024; k0 += 32) {
      __syncthreads();
      {
        const float* ap = x + (size_t)(m0 + sr) * 1024 + k0 + q0 * 8;
        float xs[16];
        *(float4*)&xs[0]  = *(const float4*)(ap);
        *(float4*)&xs[4]  = *(const float4*)(ap + 4);
        *(float4*)&xs[8]  = *(const float4*)(ap + 8);
        *(float4*)&xs[12] = *(const float4*)(ap + 12);
        bf16x8 h0, h1, m0v, m1v, l0, l1;
#pragma unroll
        for (int j = 0; j < 8; ++j) {
          ushort hu, mu, lu;
          split3t(xs[j], hu, mu, lu);
          h0[j] = (short)hu; m0v[j] = (short)mu; l0[j] = (short)lu;
          split3t(xs[j + 8], hu, mu, lu);
          h1[j] = (short)hu; m1v[j] = (short)mu; l1[j] = (short)lu;
        }
        *(bf16x8*)&As[wb0] = h0;          *(bf16x8*)&As[wb1] = h1;
        *(bf16x8*)&As[4096 + wb0] = m0v;  *(bf16x8*)&As[4096 + wb1] = m1v;
        *(bf16x8*)&As[8192 + wb0] = l0;   *(bf16x8*)&As[8192 + wb1] = l1;
#pragma unroll
        for (int s = 0; s < 3; ++s) {
          const ushort* bp = wt + ((size_t)s << 20) + (size_t)(n0 + sr) * 1024 + k0 + q0 * 8;
          *(bf16x8*)&Bs[s * 4096 + wb0] = *(const bf16x8*)(bp);
          *(bf16x8*)&Bs[s * 4096 + wb1] = *(const bf16x8*)(bp + 8);
        }
      }
      __syncthreads();
      bf16x8 af[4][3];
#pragma unroll
      for (int tm = 0; tm < 4; ++tm)
#pragma unroll
        for (int s = 0; s < 3; ++s)
          af[tm][s] = *(const bf16x8*)&As[s * 4096 + FRAG_IDX(wm * 4 + tm, quad, l15)];
#pragma unroll
      for (int tn = 0; tn < 4; ++tn) {
        const int bi = FRAG_IDX(wn * 4 + tn, quad, l15);
        bf16x8 b0 = *(const bf16x8*)&Bs[bi];
        bf16x8 b1 = *(const bf16x8*)&Bs[4096 + bi];
        bf16x8 b2 = *(const bf16x8*)&Bs[8192 + bi];
#pragma unroll
        for (int tm = 0; tm < 4; ++tm) {
          f32x4 a = acc[tm][tn];
          a = __builtin_amdgcn_mfma_f32_16x16x32_bf16(af[tm][0], b0, a, 0, 0, 0);
          a = __builtin_amdgcn_mfma_f32_16x16x32_bf16(af[tm][0], b1, a, 0, 0, 0);
          a = __builtin_amdgcn_mfma_f32_16x16x32_bf16(af[tm][1], b0, a, 0, 0, 0);
          a = __builtin_amdgcn_mfma_f32_16x16x32_bf16(af[tm][0], b2, a, 0, 0, 0);
          a = __builtin_amdgcn_mfma_f32_16x16x32_bf16(af[tm][1], b1, a, 0, 0, 0);
          a = __builtin_amdgcn_mfma_f32_16x16x32_bf16(af[tm][2], b0, a, 0, 0, 0);
          acc[tm][tn] = a;
        }
      }
    }
#pragma unroll
    for (int tm = 0; tm < 4; ++tm) {
#pragma unroll
      for (int tn = 0; tn < 4; ++tn) {
#pragma unroll
        for (int r = 0; r < 4; ++r) {
          int m = m0 + wm * 64 + tm * 16 + quad * 4 + r;
          int n = n0 + wn * 64 + tn * 16 + l15;
          int b = m >> 10, t = m & 1023, h = n >> 6, f = n & 63;
          size_t idx = (((size_t)(b * 16 + h)) * 1024 + t) * 64 + f;
          if (zi == 0) {
            qf[idx] = acc[tm][tn][r];
          } else {
            ushort hu, mu, lu;
            split3(acc[tm][tn][r], hu, mu, lu);
            kh[idx] = hu; km[idx] = mu; kl[idx] = lu;
          }
        }
      }
    }
  } else {
    const ushort* wt = wT + (size_t)6 * (1u << 20);
    for (int k0 = 0; k0 < 1024; k0 += 32) {
      __syncthreads();
      {
        const float* ap = x + (size_t)(m0 + sr) * 1024 + k0 + q0 * 8;
        float xs[16];
        *(float4*)&xs[0]  = *(const float4*)(ap);
        *(float4*)&xs[4]  = *(const float4*)(ap + 4);
        *(float4*)&xs[8]  = *(const float4*)(ap + 8);
        *(float4*)&xs[12] = *(const float4*)(ap + 12);
        bf16x8 h0, h1;
#pragma unroll
        for (int j = 0; j < 8; ++j) {
          h0[j] = (short)f2bf(xs[j]);
          h1[j] = (short)f2bf(xs[j + 8]);
        }
        *(bf16x8*)&As[wb0] = h0; *(bf16x8*)&As[wb1] = h1;
        const ushort* bp = wt + (size_t)(n0 + sr) * 1024 + k0 + q0 * 8;
        *(bf16x8*)&Bs[wb0] = *(const bf16x8*)(bp);
        *(bf16x8*)&Bs[wb1] = *(const bf16x8*)(bp + 8);
      }
      __syncthreads();
      bf16x8 af[4];
#pragma unroll
      for (int tm = 0; tm < 4; ++tm)
        af[tm] = *(const bf16x8*)&As[FRAG_IDX(wm * 4 + tm, quad, l15)];
#pragma unroll
      for (int tn = 0; tn < 4; ++tn) {
        bf16x8 b0 = *(const bf16x8*)&Bs[FRAG_IDX(wn * 4 + tn, quad, l15)];
#pragma unroll
        for (int tm = 0; tm < 4; ++tm)
          acc[tm][tn] = __builtin_amdgcn_mfma_f32_16x16x32_bf16(af[tm], b0, acc[tm][tn], 0, 0, 0);
      }
    }
#pragma unroll
    for (int tm = 0; tm < 4; ++tm) {
#pragma unroll
      for (int tn = 0; tn < 4; ++tn) {
#pragma unroll
        for (int r = 0; r < 4; ++r) {
          int m = m0 + wm * 64 + tm * 16 + quad * 4 + r;
          int n = n0 + wn * 64 + tn * 16 + l15;
          int b = m >> 10, t = m & 1023, h = n >> 6, f = n & 63;
          vt[(((size_t)(b * 16 + h)) * 64 + f) * 1024 + t] = f2bf(acc[tm][tn][r]);
        }
      }
    }
  }
}

// ---------------------------------------------------------------------------
// Flash attention (unchanged from round 9).
// ---------------------------------------------------------------------------
__global__ __launch_bounds__(512) void attn_mfma(
    const float* __restrict__ qf, const ushort* __restrict__ kh,
    const ushort* __restrict__ km, const ushort* __restrict__ kl,
    const ushort* __restrict__ vt, ushort* __restrict__ zh, ushort* __restrict__ zl)
{
  __shared__ ushort Ks[3][64][68];
  __shared__ ushort Vs[64][68];
  __shared__ ushort Pl[8][16][68];

  const int tid = threadIdx.x;
  const int wave = tid >> 6, lane = tid & 63;
  const int l15 = lane & 15, quad = lane >> 4;
  const int bh = blockIdx.y;
  const int qbase = blockIdx.x * 128;

  bf16x8 aqh[2], aqm[2], aql[2];
  {
    const int qrow = qbase + wave * 16 + l15;
    const float* qp = qf + ((size_t)bh * Tc + qrow) * Fc;
#pragma unroll
    for (int ks = 0; ks < 2; ++ks) {
      int f0 = ks * 32 + quad * 8;
      float4 x0 = *(const float4*)(qp + f0);
      float4 x1 = *(const float4*)(qp + f0 + 4);
      float xs[8] = {x0.x, x0.y, x0.z, x0.w, x1.x, x1.y, x1.z, x1.w};
#pragma unroll
      for (int j = 0; j < 8; ++j) {
        ushort hu, mu, lu;
        split3(xs[j], hu, mu, lu);
        aqh[ks][j] = (short)hu; aqm[ks][j] = (short)mu; aql[ks][j] = (short)lu;
      }
    }
  }

  f32x4 o[4] = {{0,0,0,0},{0,0,0,0},{0,0,0,0},{0,0,0,0}};
  float m_run[4], l_run[4];
#pragma unroll
  for (int r = 0; r < 4; ++r) { m_run[r] = -1e30f; l_run[r] = 0.f; }

  const int srow = tid >> 3, sc8 = tid & 7;
  const size_t kbase = (size_t)bh * Tc * Fc;
  const size_t vbase = (size_t)bh * Fc * Tc;
  const ushort* kp0 = kh + kbase + (size_t)srow * Fc + sc8 * 8;
  const ushort* kp1 = km + kbase + (size_t)srow * Fc + sc8 * 8;
  const ushort* kp2 = kl + kbase + (size_t)srow * Fc + sc8 * 8;
  const ushort* vp  = vt + vbase + (size_t)srow * Tc + sc8 * 8;

  for (int kt = 0; kt < Tc; kt += 64) {
    __syncthreads();
    {
      const size_t ko = (size_t)kt * Fc;
      *(bf16x8*)&Ks[0][srow][sc8 * 8] = *(const bf16x8*)(kp0 + ko);
      *(bf16x8*)&Ks[1][srow][sc8 * 8] = *(const bf16x8*)(kp1 + ko);
      *(bf16x8*)&Ks[2][srow][sc8 * 8] = *(const bf16x8*)(kp2 + ko);
      *(bf16x8*)&Vs[srow][sc8 * 8]    = *(const bf16x8*)(vp + kt);
    }
    __syncthreads();

    f32x4 sacc[4] = {{0,0,0,0},{0,0,0,0},{0,0,0,0},{0,0,0,0}};
#pragma unroll
    for (int nt = 0; nt < 4; ++nt) {
      int key = nt * 16 + l15;
#pragma unroll
      for (int ks = 0; ks < 2; ++ks) {
        int f0 = ks * 32 + quad * 8;
        bf16x8 bh_ = *(const bf16x8*)&Ks[0][key][f0];
        bf16x8 bm_ = *(const bf16x8*)&Ks[1][key][f0];
        bf16x8 bl_ = *(const bf16x8*)&Ks[2][key][f0];
        sacc[nt] = __builtin_amdgcn_mfma_f32_16x16x32_bf16(aqh[ks], bh_, sacc[nt], 0, 0, 0);
        sacc[nt] = __builtin_amdgcn_mfma_f32_16x16x32_bf16(aqh[ks], bm_, sacc[nt], 0, 0, 0);
        sacc[nt] = __builtin_amdgcn_mfma_f32_16x16x32_bf16(aqm[ks], bh_, sacc[nt], 0, 0, 0);
        sacc[nt] = __builtin_amdgcn_mfma_f32_16x16x32_bf16(aqh[ks], bl_, sacc[nt], 0, 0, 0);
        sacc[nt] = __builtin_amdgcn_mfma_f32_16x16x32_bf16(aqm[ks], bm_, sacc[nt], 0, 0, 0);
        sacc[nt] = __builtin_amdgcn_mfma_f32_16x16x32_bf16(aql[ks], bh_, sacc[nt], 0, 0, 0);
      }
    }

    const int rowg0 = qbase + wave * 16 + quad * 4;
    float mx[4];
#pragma unroll
    for (int r = 0; r < 4; ++r) mx[r] = -1e30f;
#pragma unroll
    for (int nt = 0; nt < 4; ++nt) {
      int key = kt + nt * 16 + l15;
#pragma unroll
      for (int r = 0; r < 4; ++r) {
        float s = sacc[nt][r];
        if (key > rowg0 + r) s *= -1.0e9f + 1.0f;
        s *= 0.125f;
        sacc[nt][r] = s;
        mx[r] = fmaxf(mx[r], s);
      }
    }
#pragma unroll
    for (int r = 0; r < 4; ++r)
#pragma unroll
      for (int d = 1; d < 16; d <<= 1) mx[r] = fmaxf(mx[r], __shfl_xor(mx[r], d));

    float corr[4], ps[4];
#pragma unroll
    for (int r = 0; r < 4; ++r) {
      float m2 = fmaxf(m_run[r], mx[r]);
      corr[r] = __expf(m_run[r] - m2);
      m_run[r] = m2;
      ps[r] = 0.f;
    }
#pragma unroll
    for (int nt = 0; nt < 4; ++nt) {
#pragma unroll
      for (int r = 0; r < 4; ++r) {
        float p = __expf(sacc[nt][r] - m_run[r]);
        ps[r] += p;
        Pl[wave][quad * 4 + r][nt * 16 + l15] = f2bf(p);
      }
    }
#pragma unroll
    for (int r = 0; r < 4; ++r) {
#pragma unroll
      for (int d = 1; d < 16; d <<= 1) ps[r] += __shfl_xor(ps[r], d);
      l_run[r] = l_run[r] * corr[r] + ps[r];
#pragma unroll
      for (int ft = 0; ft < 4; ++ft) o[ft][r] *= corr[r];
    }

#pragma unroll
    for (int ks2 = 0; ks2 < 2; ++ks2) {
      bf16x8 pa = *(const bf16x8*)&Pl[wave][l15][ks2 * 32 + quad * 8];
#pragma unroll
      for (int ft = 0; ft < 4; ++ft) {
        bf16x8 vb = *(const bf16x8*)&Vs[ft * 16 + l15][ks2 * 32 + quad * 8];
        o[ft] = __builtin_amdgcn_mfma_f32_16x16x32_bf16(pa, vb, o[ft], 0, 0, 0);
      }
    }
  }

  const int b = bh >> 4, h = bh & 15;
#pragma unroll
  for (int r = 0; r < 4; ++r) {
    float inv = 1.f / l_run[r];
    int row = qbase + wave * 16 + quad * 4 + r;
    size_t base = ((size_t)(b * Tc + row)) * Ec + h * Fc;
#pragma unroll
    for (int ft = 0; ft < 4; ++ft) {
      ushort hu, lu;
      split2(o[ft][r] * inv, hu, lu);
      zh[base + ft * 16 + l15] = hu;
      zl[base + ft * 16 + l15] = lu;
    }
  }
}

// ---------------------------------------------------------------------------
// fr GEMM (unchanged from round 9).
// ---------------------------------------------------------------------------
__global__ __launch_bounds__(256) void gemm_fr_mfma(
    const ushort* __restrict__ zh, const ushort* __restrict__ zl,
    const ushort* __restrict__ frT, const float* __restrict__ x,
    float* __restrict__ s1, float2* __restrict__ part)
{
  const int bb = blockIdx.z;
  const int m0 = blockIdx.x * 128, n0 = blockIdx.y * 128;
  __shared__ ushort Ah[4096], Al[4096], Bh[4096], Bl[4096];
  __shared__ float2 red[256];
  const int tid = threadIdx.x;
  const int wave = tid >> 6, lane = tid & 63, l15 = lane & 15, quad = lane >> 4;
  const int wm = wave >> 1, wn = wave & 1;
  const int sr = tid >> 1, q0 = (tid & 1) * 2;
  const int wb0 = FRAG_IDX(sr >> 4, q0, sr & 15);
  const int wb1 = FRAG_IDX(sr >> 4, q0 + 1, sr & 15);
  f32x4 acc[4][4] = {};
  const size_t abase = ((size_t)bb * 1024 + m0 + sr) * 1024 + q0 * 8;
  const size_t bbase = ((size_t)bb * 1024 + n0 + sr) * 1024 + q0 * 8;
  const ushort* blp = frT + (4u << 20);
  for (int k0 = 0; k0 < 1024; k0 += 32) {
    __syncthreads();
    {
      *(bf16x8*)&Ah[wb0] = *(const bf16x8*)(zh + abase + k0);
      *(bf16x8*)&Ah[wb1] = *(const bf16x8*)(zh + abase + k0 + 8);
      *(bf16x8*)&Al[wb0] = *(const bf16x8*)(zl + abase + k0);
      *(bf16x8*)&Al[wb1] = *(const bf16x8*)(zl + abase + k0 + 8);
      *(bf16x8*)&Bh[wb0] = *(const bf16x8*)(frT + bbase + k0);
      *(bf16x8*)&Bh[wb1] = *(const bf16x8*)(frT + bbase + k0 + 8);
      *(bf16x8*)&Bl[wb0] = *(const bf16x8*)(blp + bbase + k0);
      *(bf16x8*)&Bl[wb1] = *(const bf16x8*)(blp + bbase + k0 + 8);
    }
    __syncthreads();
    bf16x8 ah[4], al[4];
#pragma unroll
    for (int tm = 0; tm < 4; ++tm) {
      ah[tm] = *(const bf16x8*)&Ah[FRAG_IDX(wm * 4 + tm, quad, l15)];
      al[tm] = *(const bf16x8*)&Al[FRAG_IDX(wm * 4 + tm, quad, l15)];
    }
#pragma unroll
    for (int tn = 0; tn < 4; ++tn) {
      const int bi = FRAG_IDX(wn * 4 + tn, quad, l15);
      bf16x8 b0 = *(const bf16x8*)&Bh[bi];
      bf16x8 b1 = *(const bf16x8*)&Bl[bi];
#pragma unroll
      for (int tm = 0; tm < 4; ++tm) {
        f32x4 a = acc[tm][tn];
        a = __builtin_amdgcn_mfma_f32_16x16x32_bf16(ah[tm], b0, a, 0, 0, 0);
        a = __builtin_amdgcn_mfma_f32_16x16x32_bf16(ah[tm], b1, a, 0, 0, 0);
        a = __builtin_amdgcn_mfma_f32_16x16x32_bf16(al[tm], b0, a, 0, 0, 0);
        acc[tm][tn] = a;
      }
    }
  }
  float sum = 0.f, sq = 0.f;
#pragma unroll
  for (int tm = 0; tm < 4; ++tm) {
#pragma unroll
    for (int tn = 0; tn < 4; ++tn) {
#pragma unroll
      for (int r = 0; r < 4; ++r) {
        int m = m0 + wm * 64 + tm * 16 + quad * 4 + r;
        int n = n0 + wn * 64 + tn * 16 + l15;
        size_t idx = ((size_t)bb * 1024 + m) * 1024 + n;
        float o = x[idx] + acc[tm][tn][r];
        s1[idx] = o;
        sum += o; sq += o * o;
      }
    }
  }
  red[tid] = make_float2(sum, sq);
  __syncthreads();
  for (int s = 128; s > 0; s >>= 1) {
    if (tid < s) { red[tid].x += red[tid + s].x; red[tid].y += red[tid + s].y; }
    __syncthreads();
  }
  if (tid == 0) part[(bb * 8 + blockIdx.x) * 8 + blockIdx.y] = red[0];
}

// ---------------------------------------------------------------------------
// ff GEMM (unchanged from round 9).
// ---------------------------------------------------------------------------
__global__ __launch_bounds__(256) void gemm_ff_mfma(
    const ushort* __restrict__ z1h, const ushort* __restrict__ z1l,
    const ushort* __restrict__ fwh, const ushort* __restrict__ fwl,
    const float* __restrict__ ffb, float* __restrict__ s2,
    float2* __restrict__ part)
{
  const int m0 = blockIdx.x * 128, n0 = blockIdx.y * 128;
  __shared__ ushort Ah[4096], Al[4096], Bh[4096], Bl[4096];
  __shared__ float2 red[256];
  const int tid = threadIdx.x;
  const int wave = tid >> 6, lane = tid & 63, l15 = lane & 15, quad = lane >> 4;
  const int wm = wave >> 1, wn = wave & 1;
  const int sr = tid >> 1, q0 = (tid & 1) * 2;
  const int wb0 = FRAG_IDX(sr >> 4, q0, sr & 15);
  const int wb1 = FRAG_IDX(sr >> 4, q0 + 1, sr & 15);
  f32x4 acc[4][4] = {};
  const size_t abase = (size_t)(m0 + sr) * 1024 + q0 * 8;
  const size_t bbase = (size_t)(n0 + sr) * 1024 + q0 * 8;
  for (int k0 = 0; k0 < 1024; k0 += 32) {
    __syncthreads();
    {
      *(bf16x8*)&Ah[wb0] = *(const bf16x8*)(z1h + abase + k0);
      *(bf16x8*)&Ah[wb1] = *(const bf16x8*)(z1h + abase + k0 + 8);
      *(bf16x8*)&Al[wb0] = *(const bf16x8*)(z1l + abase + k0);
      *(bf16x8*)&Al[wb1] = *(const bf16x8*)(z1l + abase + k0 + 8);
      *(bf16x8*)&Bh[wb0] = *(const bf16x8*)(fwh + bbase + k0);
      *(bf16x8*)&Bh[wb1] = *(const bf16x8*)(fwh + bbase + k0 + 8);
      *(bf16x8*)&Bl[wb0] = *(const bf16x8*)(fwl + bbase + k0);
      *(bf16x8*)&Bl[wb1] = *(const bf16x8*)(fwl + bbase + k0 + 8);
    }
    __syncthreads();
    bf16x8 ah[4], al[4];
#pragma unroll
    for (int tm = 0; tm < 4; ++tm) {
      ah[tm] = *(const bf16x8*)&Ah[FRAG_IDX(wm * 4 + tm, quad, l15)];
      al[tm] = *(const bf16x8*)&Al[FRAG_IDX(wm * 4 + tm, quad, l15)];
    }
#pragma unroll
    for (int tn = 0; tn < 4; ++tn) {
      const int bi = FRAG_IDX(wn * 4 + tn, quad, l15);
      bf16x8 b0 = *(const bf16x8*)&Bh[bi];
      bf16x8 b1 = *(const bf16x8*)&Bl[bi];
#pragma unroll
      for (int tm = 0; tm < 4; ++tm) {
        f32x4 a = acc[tm][tn];
        a = __builtin_amdgcn_mfma_f32_16x16x32_bf16(ah[tm], b0, a, 0, 0, 0);
        a = __builtin_amdgcn_mfma_f32_16x16x32_bf16(ah[tm], b1, a, 0, 0, 0);
        a = __builtin_amdgcn_mfma_f32_16x16x32_bf16(al[tm], b0, a, 0, 0, 0);
        acc[tm][tn] = a;
      }
    }
  }
  float sum = 0.f, sq = 0.f;
#pragma unroll
  for (int tm = 0; tm < 4; ++tm) {
#pragma unroll
    for (int tn = 0; tn < 4; ++tn) {
#pragma unroll
      for (int r = 0; r < 4; ++r) {
        int m = m0 + wm * 64 + tm * 16 + quad * 4 + r;
        int n = n0 + wn * 64 + tn * 16 + l15;
        size_t idx = (size_t)m * 1024 + n;
        float z1v = bf2f(z1h[idx]) + bf2f(z1l[idx]);
        float o = z1v + fmaxf(acc[tm][tn][r] + ffb[n], 0.f);
        s2[idx] = o;
        sum += o; sq += o * o;
      }
    }
  }
  red[tid] = make_float2(sum, sq);
  __syncthreads();
  for (int s = 128; s > 0; s >>= 1) {
    if (tid < s) { red[tid].x += red[tid + s].x; red[tid].y += red[tid + s].y; }
    __syncthreads();
  }
  if (tid == 0) part[blockIdx.x * 8 + blockIdx.y] = red[0];
}

__global__ __launch_bounds__(256) void ln_stats(
    const float2* __restrict__ part, float2* __restrict__ stats, int npart)
{
  __shared__ double sd[256], sq[256];
  const int tid = threadIdx.x;
  float2 p = (tid < npart) ? part[blockIdx.x * npart + tid] : make_float2(0.f, 0.f);
  sd[tid] = (double)p.x; sq[tid] = (double)p.y;
  __syncthreads();
  for (int s = 128; s > 0; s >>= 1) {
    if (tid < s) { sd[tid] += sd[tid + s]; sq[tid] += sq[tid + s]; }
    __syncthreads();
  }
  if (tid == 0) {
    const double n = (double)Tc * Ec;
    double mean = sd[0] / n;
    double var = sq[0] / n - mean * mean;
    if (var < 0.0) var = 0.0;
    double rs = 1.0 / sqrt(var + 1e-5);
    stats[blockIdx.x] = make_float2((float)mean, (float)rs);
  }
}

// ln_norm -> split2 pair; blocks >= 4096 instead split2 ffw (folded launch;
// runs after gemm_fr so fwh/fwl @48-52MB no longer alias live zh).
__global__ __launch_bounds__(256) void ln_norm_split(
    const float* __restrict__ s, const float2* __restrict__ stats,
    const float* __restrict__ w, const float* __restrict__ bias,
    ushort* __restrict__ oh, ushort* __restrict__ ol,
    const float* __restrict__ ffw, ushort* __restrict__ fwh, ushort* __restrict__ fwl)
{
  if (blockIdx.x >= 4096) {
    int i = (blockIdx.x - 4096) * 256 + threadIdx.x;  // 0..65535
#pragma unroll
    for (int j = 0; j < 4; ++j) {
      int idx = i * 4 + j;  // 262144 float4s total
      float4 v = ((const float4*)ffw)[idx];
      ushort4 h, l;
      split2(v.x, h.x, l.x); split2(v.y, h.y, l.y);
      split2(v.z, h.z, l.z); split2(v.w, h.w, l.w);
      ((ushort4*)fwh)[idx] = h; ((ushort4*)fwl)[idx] = l;
    }
    return;
  }
  int i = blockIdx.x * 256 + threadIdx.x;
  int b = i >> 18;
  int te4 = i & ((1 << 18) - 1);
  float2 st = stats[b];
  float4 sv = ((const float4*)s)[i];
  float4 wv = ((const float4*)w)[te4];
  float4 bv = ((const float4*)bias)[te4];
  float4 o;
  o.x = (sv.x - st.x) * st.y * wv.x + bv.x;
  o.y = (sv.y - st.x) * st.y * wv.y + bv.y;
  o.z = (sv.z - st.x) * st.y * wv.z + bv.z;
  o.w = (sv.w - st.x) * st.y * wv.w + bv.w;
  ushort4 h, l;
  split2(o.x, h.x, l.x); split2(o.y, h.y, l.y);
  split2(o.z, h.z, l.z); split2(o.w, h.w, l.w);
  ((ushort4*)oh)[i] = h; ((ushort4*)ol)[i] = l;
}

__global__ __launch_bounds__(256) void ln_norm(
    const float* __restrict__ s, const float2* __restrict__ stats,
    const float* __restrict__ w, const float* __restrict__ bias,
    float* __restrict__ out)
{
  int i = blockIdx.x * 256 + threadIdx.x;
  if (i >= (Bc * Tc * Ec) / 4) return;
  int b = i >> 18;
  int te4 = i & ((1 << 18) - 1);
  float2 st = stats[b];
  float4 sv = ((const float4*)s)[i];
  float4 wv = ((const float4*)w)[te4];
  float4 bv = ((const float4*)bias)[te4];
  float4 o;
  o.x = (sv.x - st.x) * st.y * wv.x + bv.x;
  o.y = (sv.y - st.x) * st.y * wv.y + bv.y;
  o.z = (sv.z - st.x) * st.y * wv.z + bv.z;
  o.w = (sv.w - st.x) * st.y * wv.w + bv.w;
  ((float4*)out)[i] = o;
}

// ---------------------------------------------------------------------------
extern "C" void kernel_launch(void* const* d_in, const int* in_sizes, int n_in,
                              void* d_out, int out_size, void* d_ws, size_t ws_size,
                              hipStream_t stream)
{
  const float* x    = (const float*)d_in[0];
  const float* qw   = (const float*)d_in[1];
  const float* kw   = (const float*)d_in[2];
  const float* vw   = (const float*)d_in[3];
  const float* frw  = (const float*)d_in[4];
  const float* ffw  = (const float*)d_in[5];
  const float* ffb  = (const float*)d_in[6];
  const float* ln1w = (const float*)d_in[7];
  const float* ln1b = (const float*)d_in[8];
  const float* ln2w = (const float*)d_in[9];
  const float* ln2b = (const float*)d_in[10];
  float* out = (float*)d_out;
  char* W = (char*)d_ws;

  const size_t MB = 1ull << 20;
  // Footprint: 64 MB + 16.4 KB (proven). Same phase liveness as round 9.
  float*  qf  = (float*)(W);
  ushort* kh  = (ushort*)(W + 16 * MB);
  ushort* km  = (ushort*)(W + 24 * MB);
  ushort* kl  = (ushort*)(W + 32 * MB);
  ushort* vt  = (ushort*)(W + 40 * MB);
  ushort* wT  = (ushort*)(W + 48 * MB);
  ushort* zh  = (ushort*)(W + 48 * MB);
  ushort* zl  = (ushort*)(W + 56 * MB);
  ushort* frT = (ushort*)(W + 16 * MB);
  float*  s1  = (float*)(W);
  ushort* z1h = (ushort*)(W + 16 * MB);
  ushort* z1l = (ushort*)(W + 24 * MB);
  ushort* fwh = (ushort*)(W + 48 * MB);
  ushort* fwl = (ushort*)(W + 50 * MB);
  float*  s2  = (float*)(W + 32 * MB);
  float2* part1  = (float2*)(W + 64 * MB);
  float2* part2  = part1 + 1024;
  float2* stats1 = part2 + 1024;
  float2* stats2 = stats1 + 4;

  transp_w<<<dim3(16, 16, 3), 256, 0, stream>>>(qw, kw, vw, wT);
  proj_all_mfma<<<dim3(32, 8, 3), 256, 0, stream>>>(x, wT, qf, kh, km, kl, vt);
  attn_mfma<<<dim3(8, 64), 512, 0, stream>>>(qf, kh, km, kl, vt, zh, zl);
  transp_frw<<<dim3(16, 16, 4), 256, 0, stream>>>(frw, frT);
  gemm_fr_mfma<<<dim3(8, 8, 4), 256, 0, stream>>>(zh, zl, frT, x, s1, part1);
  ln_stats<<<dim3(4), 256, 0, stream>>>(part1, stats1, 64);
  ln_norm_split<<<dim3(4352), 256, 0, stream>>>(s1, stats1, ln1w, ln1b, z1h, z1l,
                                                ffw, fwh, fwl);
  gemm_ff_mfma<<<dim3(32, 8), 256, 0, stream>>>(z1h, z1l, fwh, fwl, ffb, s2, part2);
  ln_stats<<<dim3(4), 256, 0, stream>>>(part2, stats2, 64);
  ln_norm<<<dim3(4096), 256, 0, stream>>>(s2, stats2, ln2w, ln2b, out);
}

// Round 11
// 419.229 us; speedup vs baseline: 1.2275x; 1.0234x over previous
//
#include <hip/hip_runtime.h>
#include <math.h>

constexpr int Bc = 4, Tc = 1024, Ec = 1024, Hc = 16, Fc = 64;

typedef __attribute__((ext_vector_type(8))) short bf16x8;
typedef __attribute__((ext_vector_type(4))) float f32x4;

__device__ __forceinline__ ushort f2bf(float x) {
  union { float f; unsigned u; } v; v.f = x;
  unsigned r = v.u + 0x7fffu + ((v.u >> 16) & 1u);
  return (ushort)(r >> 16);
}
__device__ __forceinline__ float bf2f(ushort h) {
  union { float f; unsigned u; } v; v.u = ((unsigned)h) << 16; return v.f;
}
__device__ __forceinline__ void split3(float x, ushort& h, ushort& m, ushort& l) {
  h = f2bf(x);
  float r1 = x - bf2f(h);
  m = f2bf(r1);
  float r2 = r1 - bf2f(m);
  l = f2bf(r2);
}
__device__ __forceinline__ void split2(float x, ushort& h, ushort& l) {
  h = f2bf(x);
  l = f2bf(x - bf2f(h));
}
// Truncation split3 (~8 VALU ops): one-sided residual < 2^-22 rel.
__device__ __forceinline__ void split3t(float x, ushort& h, ushort& m, ushort& l) {
  union { float f; unsigned u; } v; v.f = x;
  h = (ushort)(v.u >> 16);
  union { float f; unsigned u; } hf; hf.u = v.u & 0xffff0000u;
  float r1 = x - hf.f;
  union { float f; unsigned u; } v1; v1.f = r1;
  m = (ushort)(v1.u >> 16);
  union { float f; unsigned u; } mf; mf.u = v1.u & 0xffff0000u;
  float r2 = r1 - mf.f;
  union { float f; unsigned u; } v2; v2.f = r2;
  l = (ushort)(v2.u >> 16);
}

// Fragment-major LDS cell: [tile][quad(0..3)][lane(0..15)][8 ushorts]
#define FRAG_IDX(tile, quad, l) (((((tile) * 4) + (quad)) * 16 + (l)) * 8)

// ---------------------------------------------------------------------------
// Pre-transpose + split projection weights (unchanged).
// ---------------------------------------------------------------------------
__global__ __launch_bounds__(256) void transp_w(
    const float* __restrict__ qw, const float* __restrict__ kw,
    const float* __restrict__ vw, ushort* __restrict__ wT)
{
  const int zi = blockIdx.z;
  const float* src = (zi == 0) ? qw : (zi == 1) ? kw : vw;
  ushort* dst = wT + (size_t)(zi * 3) * (1u << 20);
  const int ns = (zi == 2) ? 1 : 3;
  const int h = blockIdx.y, e0 = blockIdx.x * 64;
  __shared__ float T[64][68];
  const int tid = threadIdx.x;
  {
    const int er = tid >> 4, fr = (tid & 15) * 4;
#pragma unroll
    for (int i = 0; i < 4; ++i) {
      const float4 v = *(const float4*)&src[((size_t)(h * 1024 + e0 + er + i * 16)) * 64 + fr];
      *(float4*)&T[er + i * 16][fr] = v;
    }
  }
  __syncthreads();
  const int f = tid >> 2, eo = (tid & 3) * 16;
  ushort hs[16], ms[16], ls[16];
#pragma unroll
  for (int j = 0; j < 16; ++j) split3(T[eo + j][f], hs[j], ms[j], ls[j]);
  const size_t nbase = (size_t)(h * 64 + f) * 1024 + e0 + eo;
  bf16x8 v0, v1;
#pragma unroll
  for (int j = 0; j < 8; ++j) { v0[j] = (short)hs[j]; v1[j] = (short)hs[j + 8]; }
  *(bf16x8*)&dst[nbase] = v0; *(bf16x8*)&dst[nbase + 8] = v1;
  if (ns == 3) {
#pragma unroll
    for (int j = 0; j < 8; ++j) { v0[j] = (short)ms[j]; v1[j] = (short)ms[j + 8]; }
    *(bf16x8*)&dst[(1u << 20) + nbase] = v0; *(bf16x8*)&dst[(1u << 20) + nbase + 8] = v1;
#pragma unroll
    for (int j = 0; j < 8; ++j) { v0[j] = (short)ls[j]; v1[j] = (short)ls[j + 8]; }
    *(bf16x8*)&dst[(2u << 20) + nbase] = v0; *(bf16x8*)&dst[(2u << 20) + nbase + 8] = v1;
  }
}

// ---------------------------------------------------------------------------
// Pre-transpose + split2 fr weights (unchanged).
// ---------------------------------------------------------------------------
__global__ __launch_bounds__(256) void transp_frw(
    const float* __restrict__ frw, ushort* __restrict__ frT)
{
  const int bb = blockIdx.z;
  const int e0 = blockIdx.x * 64, d0 = blockIdx.y * 64;
  __shared__ float T[64][68];
  const int tid = threadIdx.x;
  {
    const int er = tid >> 4, dr = (tid & 15) * 4;
#pragma unroll
    for (int i = 0; i < 4; ++i) {
      const float4 v = *(const float4*)&frw[((size_t)bb * 1024 + e0 + er + i * 16) * 1024 + d0 + dr];
      *(float4*)&T[er + i * 16][dr] = v;
    }
  }
  __syncthreads();
  const int d = tid >> 2, eo = (tid & 3) * 16;
  ushort hs[16], ls[16];
#pragma unroll
  for (int j = 0; j < 16; ++j) split2(T[eo + j][d], hs[j], ls[j]);
  const size_t nbase = ((size_t)bb * 1024 + d0 + d) * 1024 + e0 + eo;
  bf16x8 v0, v1;
#pragma unroll
  for (int j = 0; j < 8; ++j) { v0[j] = (short)hs[j]; v1[j] = (short)hs[j + 8]; }
  *(bf16x8*)&frT[nbase] = v0; *(bf16x8*)&frT[nbase + 8] = v1;
#pragma unroll
  for (int j = 0; j < 8; ++j) { v0[j] = (short)ls[j]; v1[j] = (short)ls[j + 8]; }
  *(bf16x8*)&frT[(4u << 20) + nbase] = v0; *(bf16x8*)&frT[(4u << 20) + nbase + 8] = v1;
}

// ---------------------------------------------------------------------------
// ALL projections in one launch (unchanged from round 10).
// ---------------------------------------------------------------------------
__global__ __launch_bounds__(256) void proj_all_mfma(
    const float* __restrict__ x, const ushort* __restrict__ wT,
    float* __restrict__ qf, ushort* __restrict__ kh,
    ushort* __restrict__ km, ushort* __restrict__ kl,
    ushort* __restrict__ vt)
{
  const int zi = blockIdx.z;
  const int m0 = blockIdx.x * 128, n0 = blockIdx.y * 128;
  __shared__ ushort As[3 * 4096];
  __shared__ ushort Bs[3 * 4096];
  const int tid = threadIdx.x;
  const int wave = tid >> 6, lane = tid & 63, l15 = lane & 15, quad = lane >> 4;
  const int wm = wave >> 1, wn = wave & 1;
  const int sr = tid >> 1, q0 = (tid & 1) * 2;
  const int wb0 = FRAG_IDX(sr >> 4, q0, sr & 15);
  const int wb1 = FRAG_IDX(sr >> 4, q0 + 1, sr & 15);
  f32x4 acc[4][4] = {};

  if (zi < 2) {
    const ushort* wt = wT + (size_t)zi * 3 * (1u << 20);
    for (int k0 = 0; k0 < 1024; k0 += 32) {
      __syncthreads();
      {
        const float* ap = x + (size_t)(m0 + sr) * 1024 + k0 + q0 * 8;
        float xs[16];
        *(float4*)&xs[0]  = *(const float4*)(ap);
        *(float4*)&xs[4]  = *(const float4*)(ap + 4);
        *(float4*)&xs[8]  = *(const float4*)(ap + 8);
        *(float4*)&xs[12] = *(const float4*)(ap + 12);
        bf16x8 h0, h1, m0v, m1v, l0, l1;
#pragma unroll
        for (int j = 0; j < 8; ++j) {
          ushort hu, mu, lu;
          split3t(xs[j], hu, mu, lu);
          h0[j] = (short)hu; m0v[j] = (short)mu; l0[j] = (short)lu;
          split3t(xs[j + 8], hu, mu, lu);
          h1[j] = (short)hu; m1v[j] = (short)mu; l1[j] = (short)lu;
        }
        *(bf16x8*)&As[wb0] = h0;          *(bf16x8*)&As[wb1] = h1;
        *(bf16x8*)&As[4096 + wb0] = m0v;  *(bf16x8*)&As[4096 + wb1] = m1v;
        *(bf16x8*)&As[8192 + wb0] = l0;   *(bf16x8*)&As[8192 + wb1] = l1;
#pragma unroll
        for (int s = 0; s < 3; ++s) {
          const ushort* bp = wt + ((size_t)s << 20) + (size_t)(n0 + sr) * 1024 + k0 + q0 * 8;
          *(bf16x8*)&Bs[s * 4096 + wb0] = *(const bf16x8*)(bp);
          *(bf16x8*)&Bs[s * 4096 + wb1] = *(const bf16x8*)(bp + 8);
        }
      }
      __syncthreads();
      bf16x8 af[4][3];
#pragma unroll
      for (int tm = 0; tm < 4; ++tm)
#pragma unroll
        for (int s = 0; s < 3; ++s)
          af[tm][s] = *(const bf16x8*)&As[s * 4096 + FRAG_IDX(wm * 4 + tm, quad, l15)];
#pragma unroll
      for (int tn = 0; tn < 4; ++tn) {
        const int bi = FRAG_IDX(wn * 4 + tn, quad, l15);
        bf16x8 b0 = *(const bf16x8*)&Bs[bi];
        bf16x8 b1 = *(const bf16x8*)&Bs[4096 + bi];
        bf16x8 b2 = *(const bf16x8*)&Bs[8192 + bi];
#pragma unroll
        for (int tm = 0; tm < 4; ++tm) {
          f32x4 a = acc[tm][tn];
          a = __builtin_amdgcn_mfma_f32_16x16x32_bf16(af[tm][0], b0, a, 0, 0, 0);
          a = __builtin_amdgcn_mfma_f32_16x16x32_bf16(af[tm][0], b1, a, 0, 0, 0);
          a = __builtin_amdgcn_mfma_f32_16x16x32_bf16(af[tm][1], b0, a, 0, 0, 0);
          a = __builtin_amdgcn_mfma_f32_16x16x32_bf16(af[tm][0], b2, a, 0, 0, 0);
          a = __builtin_amdgcn_mfma_f32_16x16x32_bf16(af[tm][1], b1, a, 0, 0, 0);
          a = __builtin_amdgcn_mfma_f32_16x16x32_bf16(af[tm][2], b0, a, 0, 0, 0);
          acc[tm][tn] = a;
        }
      }
    }
#pragma unroll
    for (int tm = 0; tm < 4; ++tm) {
#pragma unroll
      for (int tn = 0; tn < 4; ++tn) {
#pragma unroll
        for (int r = 0; r < 4; ++r) {
          int m = m0 + wm * 64 + tm * 16 + quad * 4 + r;
          int n = n0 + wn * 64 + tn * 16 + l15;
          int b = m >> 10, t = m & 1023, h = n >> 6, f = n & 63;
          size_t idx = (((size_t)(b * 16 + h)) * 1024 + t) * 64 + f;
          if (zi == 0) {
            qf[idx] = acc[tm][tn][r];
          } else {
            ushort hu, mu, lu;
            split3(acc[tm][tn][r], hu, mu, lu);
            kh[idx] = hu; km[idx] = mu; kl[idx] = lu;
          }
        }
      }
    }
  } else {
    const ushort* wt = wT + (size_t)6 * (1u << 20);
    for (int k0 = 0; k0 < 1024; k0 += 32) {
      __syncthreads();
      {
        const float* ap = x + (size_t)(m0 + sr) * 1024 + k0 + q0 * 8;
        float xs[16];
        *(float4*)&xs[0]  = *(const float4*)(ap);
        *(float4*)&xs[4]  = *(const float4*)(ap + 4);
        *(float4*)&xs[8]  = *(const float4*)(ap + 8);
        *(float4*)&xs[12] = *(const float4*)(ap + 12);
        bf16x8 h0, h1;
#pragma unroll
        for (int j = 0; j < 8; ++j) {
          h0[j] = (short)f2bf(xs[j]);
          h1[j] = (short)f2bf(xs[j + 8]);
        }
        *(bf16x8*)&As[wb0] = h0; *(bf16x8*)&As[wb1] = h1;
        const ushort* bp = wt + (size_t)(n0 + sr) * 1024 + k0 + q0 * 8;
        *(bf16x8*)&Bs[wb0] = *(const bf16x8*)(bp);
        *(bf16x8*)&Bs[wb1] = *(const bf16x8*)(bp + 8);
      }
      __syncthreads();
      bf16x8 af[4];
#pragma unroll
      for (int tm = 0; tm < 4; ++tm)
        af[tm] = *(const bf16x8*)&As[FRAG_IDX(wm * 4 + tm, quad, l15)];
#pragma unroll
      for (int tn = 0; tn < 4; ++tn) {
        bf16x8 b0 = *(const bf16x8*)&Bs[FRAG_IDX(wn * 4 + tn, quad, l15)];
#pragma unroll
        for (int tm = 0; tm < 4; ++tm)
          acc[tm][tn] = __builtin_amdgcn_mfma_f32_16x16x32_bf16(af[tm], b0, acc[tm][tn], 0, 0, 0);
      }
    }
#pragma unroll
    for (int tm = 0; tm < 4; ++tm) {
#pragma unroll
      for (int tn = 0; tn < 4; ++tn) {
#pragma unroll
        for (int r = 0; r < 4; ++r) {
          int m = m0 + wm * 64 + tm * 16 + quad * 4 + r;
          int n = n0 + wn * 64 + tn * 16 + l15;
          int b = m >> 10, t = m & 1023, h = n >> 6, f = n & 63;
          vt[(((size_t)(b * 16 + h)) * 64 + f) * 1024 + t] = f2bf(acc[tm][tn][r]);
        }
      }
    }
  }
}

// ---------------------------------------------------------------------------
// Flash attention (unchanged from round 9/10).
// ---------------------------------------------------------------------------
__global__ __launch_bounds__(512) void attn_mfma(
    const float* __restrict__ qf, const ushort* __restrict__ kh,
    const ushort* __restrict__ km, const ushort* __restrict__ kl,
    const ushort* __restrict__ vt, ushort* __restrict__ zh, ushort* __restrict__ zl)
{
  __shared__ ushort Ks[3][64][68];
  __shared__ ushort Vs[64][68];
  __shared__ ushort Pl[8][16][68];

  const int tid = threadIdx.x;
  const int wave = tid >> 6, lane = tid & 63;
  const int l15 = lane & 15, quad = lane >> 4;
  const int bh = blockIdx.y;
  const int qbase = blockIdx.x * 128;

  bf16x8 aqh[2], aqm[2], aql[2];
  {
    const int qrow = qbase + wave * 16 + l15;
    const float* qp = qf + ((size_t)bh * Tc + qrow) * Fc;
#pragma unroll
    for (int ks = 0; ks < 2; ++ks) {
      int f0 = ks * 32 + quad * 8;
      float4 x0 = *(const float4*)(qp + f0);
      float4 x1 = *(const float4*)(qp + f0 + 4);
      float xs[8] = {x0.x, x0.y, x0.z, x0.w, x1.x, x1.y, x1.z, x1.w};
#pragma unroll
      for (int j = 0; j < 8; ++j) {
        ushort hu, mu, lu;
        split3(xs[j], hu, mu, lu);
        aqh[ks][j] = (short)hu; aqm[ks][j] = (short)mu; aql[ks][j] = (short)lu;
      }
    }
  }

  f32x4 o[4] = {{0,0,0,0},{0,0,0,0},{0,0,0,0},{0,0,0,0}};
  float m_run[4], l_run[4];
#pragma unroll
  for (int r = 0; r < 4; ++r) { m_run[r] = -1e30f; l_run[r] = 0.f; }

  const int srow = tid >> 3, sc8 = tid & 7;
  const size_t kbase = (size_t)bh * Tc * Fc;
  const size_t vbase = (size_t)bh * Fc * Tc;
  const ushort* kp0 = kh + kbase + (size_t)srow * Fc + sc8 * 8;
  const ushort* kp1 = km + kbase + (size_t)srow * Fc + sc8 * 8;
  const ushort* kp2 = kl + kbase + (size_t)srow * Fc + sc8 * 8;
  const ushort* vp  = vt + vbase + (size_t)srow * Tc + sc8 * 8;

  for (int kt = 0; kt < Tc; kt += 64) {
    __syncthreads();
    {
      const size_t ko = (size_t)kt * Fc;
      *(bf16x8*)&Ks[0][srow][sc8 * 8] = *(const bf16x8*)(kp0 + ko);
      *(bf16x8*)&Ks[1][srow][sc8 * 8] = *(const bf16x8*)(kp1 + ko);
      *(bf16x8*)&Ks[2][srow][sc8 * 8] = *(const bf16x8*)(kp2 + ko);
      *(bf16x8*)&Vs[srow][sc8 * 8]    = *(const bf16x8*)(vp + kt);
    }
    __syncthreads();

    f32x4 sacc[4] = {{0,0,0,0},{0,0,0,0},{0,0,0,0},{0,0,0,0}};
#pragma unroll
    for (int nt = 0; nt < 4; ++nt) {
      int key = nt * 16 + l15;
#pragma unroll
      for (int ks = 0; ks < 2; ++ks) {
        int f0 = ks * 32 + quad * 8;
        bf16x8 bh_ = *(const bf16x8*)&Ks[0][key][f0];
        bf16x8 bm_ = *(const bf16x8*)&Ks[1][key][f0];
        bf16x8 bl_ = *(const bf16x8*)&Ks[2][key][f0];
        sacc[nt] = __builtin_amdgcn_mfma_f32_16x16x32_bf16(aqh[ks], bh_, sacc[nt], 0, 0, 0);
        sacc[nt] = __builtin_amdgcn_mfma_f32_16x16x32_bf16(aqh[ks], bm_, sacc[nt], 0, 0, 0);
        sacc[nt] = __builtin_amdgcn_mfma_f32_16x16x32_bf16(aqm[ks], bh_, sacc[nt], 0, 0, 0);
        sacc[nt] = __builtin_amdgcn_mfma_f32_16x16x32_bf16(aqh[ks], bl_, sacc[nt], 0, 0, 0);
        sacc[nt] = __builtin_amdgcn_mfma_f32_16x16x32_bf16(aqm[ks], bm_, sacc[nt], 0, 0, 0);
        sacc[nt] = __builtin_amdgcn_mfma_f32_16x16x32_bf16(aql[ks], bh_, sacc[nt], 0, 0, 0);
      }
    }

    const int rowg0 = qbase + wave * 16 + quad * 4;
    float mx[4];
#pragma unroll
    for (int r = 0; r < 4; ++r) mx[r] = -1e30f;
#pragma unroll
    for (int nt = 0; nt < 4; ++nt) {
      int key = kt + nt * 16 + l15;
#pragma unroll
      for (int r = 0; r < 4; ++r) {
        float s = sacc[nt][r];
        if (key > rowg0 + r) s *= -1.0e9f + 1.0f;
        s *= 0.125f;
        sacc[nt][r] = s;
        mx[r] = fmaxf(mx[r], s);
      }
    }
#pragma unroll
    for (int r = 0; r < 4; ++r)
#pragma unroll
      for (int d = 1; d < 16; d <<= 1) mx[r] = fmaxf(mx[r], __shfl_xor(mx[r], d));

    float corr[4], ps[4];
#pragma unroll
    for (int r = 0; r < 4; ++r) {
      float m2 = fmaxf(m_run[r], mx[r]);
      corr[r] = __expf(m_run[r] - m2);
      m_run[r] = m2;
      ps[r] = 0.f;
    }
#pragma unroll
    for (int nt = 0; nt < 4; ++nt) {
#pragma unroll
      for (int r = 0; r < 4; ++r) {
        float p = __expf(sacc[nt][r] - m_run[r]);
        ps[r] += p;
        Pl[wave][quad * 4 + r][nt * 16 + l15] = f2bf(p);
      }
    }
#pragma unroll
    for (int r = 0; r < 4; ++r) {
#pragma unroll
      for (int d = 1; d < 16; d <<= 1) ps[r] += __shfl_xor(ps[r], d);
      l_run[r] = l_run[r] * corr[r] + ps[r];
#pragma unroll
      for (int ft = 0; ft < 4; ++ft) o[ft][r] *= corr[r];
    }

#pragma unroll
    for (int ks2 = 0; ks2 < 2; ++ks2) {
      bf16x8 pa = *(const bf16x8*)&Pl[wave][l15][ks2 * 32 + quad * 8];
#pragma unroll
      for (int ft = 0; ft < 4; ++ft) {
        bf16x8 vb = *(const bf16x8*)&Vs[ft * 16 + l15][ks2 * 32 + quad * 8];
        o[ft] = __builtin_amdgcn_mfma_f32_16x16x32_bf16(pa, vb, o[ft], 0, 0, 0);
      }
    }
  }

  const int b = bh >> 4, h = bh & 15;
#pragma unroll
  for (int r = 0; r < 4; ++r) {
    float inv = 1.f / l_run[r];
    int row = qbase + wave * 16 + quad * 4 + r;
    size_t base = ((size_t)(b * Tc + row)) * Ec + h * Fc;
#pragma unroll
    for (int ft = 0; ft < 4; ++ft) {
      ushort hu, lu;
      split2(o[ft][r] * inv, hu, lu);
      zh[base + ft * 16 + l15] = hu;
      zl[base + ft * 16 + l15] = lu;
    }
  }
}

// ---------------------------------------------------------------------------
// fr GEMM: tile 128x64, grid (8,16,4) = 512 blocks = 2 blocks/CU.
// Wave = 64x32 (4 tm x 2 tn), 24 MFMA/window. LDS 26 KB.
// ---------------------------------------------------------------------------
__global__ __launch_bounds__(256) void gemm_fr_mfma(
    const ushort* __restrict__ zh, const ushort* __restrict__ zl,
    const ushort* __restrict__ frT, const float* __restrict__ x,
    float* __restrict__ s1, float2* __restrict__ part)
{
  const int bb = blockIdx.z;
  const int m0 = blockIdx.x * 128, n0 = blockIdx.y * 64;
  __shared__ ushort Ah[4096], Al[4096], Bh[2048], Bl[2048];
  __shared__ float2 red[256];
  const int tid = threadIdx.x;
  const int wave = tid >> 6, lane = tid & 63, l15 = lane & 15, quad = lane >> 4;
  const int wm = wave >> 1, wn = wave & 1;
  const int sr = tid >> 1, q0 = (tid & 1) * 2;        // A staging: 128 rows x 16
  const int wb0 = FRAG_IDX(sr >> 4, q0, sr & 15);
  const int wb1 = FRAG_IDX(sr >> 4, q0 + 1, sr & 15);
  const int sr2 = tid >> 2, qb = tid & 3;             // B staging: 64 rows x 8
  const int wbB = FRAG_IDX(sr2 >> 4, qb, sr2 & 15);
  f32x4 acc[4][2] = {};
  const size_t abase = ((size_t)bb * 1024 + m0 + sr) * 1024 + q0 * 8;
  const size_t bbase = ((size_t)bb * 1024 + n0 + sr2) * 1024 + qb * 8;
  const ushort* blp = frT + (4u << 20);
  for (int k0 = 0; k0 < 1024; k0 += 32) {
    __syncthreads();
    {
      *(bf16x8*)&Ah[wb0] = *(const bf16x8*)(zh + abase + k0);
      *(bf16x8*)&Ah[wb1] = *(const bf16x8*)(zh + abase + k0 + 8);
      *(bf16x8*)&Al[wb0] = *(const bf16x8*)(zl + abase + k0);
      *(bf16x8*)&Al[wb1] = *(const bf16x8*)(zl + abase + k0 + 8);
      *(bf16x8*)&Bh[wbB] = *(const bf16x8*)(frT + bbase + k0);
      *(bf16x8*)&Bl[wbB] = *(const bf16x8*)(blp + bbase + k0);
    }
    __syncthreads();
    bf16x8 ah[4], al[4];
#pragma unroll
    for (int tm = 0; tm < 4; ++tm) {
      ah[tm] = *(const bf16x8*)&Ah[FRAG_IDX(wm * 4 + tm, quad, l15)];
      al[tm] = *(const bf16x8*)&Al[FRAG_IDX(wm * 4 + tm, quad, l15)];
    }
#pragma unroll
    for (int tn = 0; tn < 2; ++tn) {
      const int bi = FRAG_IDX(wn * 2 + tn, quad, l15);
      bf16x8 b0 = *(const bf16x8*)&Bh[bi];
      bf16x8 b1 = *(const bf16x8*)&Bl[bi];
#pragma unroll
      for (int tm = 0; tm < 4; ++tm) {
        f32x4 a = acc[tm][tn];
        a = __builtin_amdgcn_mfma_f32_16x16x32_bf16(ah[tm], b0, a, 0, 0, 0);
        a = __builtin_amdgcn_mfma_f32_16x16x32_bf16(ah[tm], b1, a, 0, 0, 0);
        a = __builtin_amdgcn_mfma_f32_16x16x32_bf16(al[tm], b0, a, 0, 0, 0);
        acc[tm][tn] = a;
      }
    }
  }
  float sum = 0.f, sq = 0.f;
#pragma unroll
  for (int tm = 0; tm < 4; ++tm) {
#pragma unroll
    for (int tn = 0; tn < 2; ++tn) {
#pragma unroll
      for (int r = 0; r < 4; ++r) {
        int m = m0 + wm * 64 + tm * 16 + quad * 4 + r;
        int n = n0 + wn * 32 + tn * 16 + l15;
        size_t idx = ((size_t)bb * 1024 + m) * 1024 + n;
        float o = x[idx] + acc[tm][tn][r];
        s1[idx] = o;
        sum += o; sq += o * o;
      }
    }
  }
  red[tid] = make_float2(sum, sq);
  __syncthreads();
  for (int s = 128; s > 0; s >>= 1) {
    if (tid < s) { red[tid].x += red[tid + s].x; red[tid].y += red[tid + s].y; }
    __syncthreads();
  }
  if (tid == 0) part[bb * 128 + blockIdx.x * 16 + blockIdx.y] = red[0];
}

// ---------------------------------------------------------------------------
// ff GEMM: tile 128x64, grid (32,16) = 512 blocks = 2 blocks/CU.
// ---------------------------------------------------------------------------
__global__ __launch_bounds__(256) void gemm_ff_mfma(
    const ushort* __restrict__ z1h, const ushort* __restrict__ z1l,
    const ushort* __restrict__ fwh, const ushort* __restrict__ fwl,
    const float* __restrict__ ffb, float* __restrict__ s2,
    float2* __restrict__ part)
{
  const int m0 = blockIdx.x * 128, n0 = blockIdx.y * 64;
  __shared__ ushort Ah[4096], Al[4096], Bh[2048], Bl[2048];
  __shared__ float2 red[256];
  const int tid = threadIdx.x;
  const int wave = tid >> 6, lane = tid & 63, l15 = lane & 15, quad = lane >> 4;
  const int wm = wave >> 1, wn = wave & 1;
  const int sr = tid >> 1, q0 = (tid & 1) * 2;
  const int wb0 = FRAG_IDX(sr >> 4, q0, sr & 15);
  const int wb1 = FRAG_IDX(sr >> 4, q0 + 1, sr & 15);
  const int sr2 = tid >> 2, qb = tid & 3;
  const int wbB = FRAG_IDX(sr2 >> 4, qb, sr2 & 15);
  f32x4 acc[4][2] = {};
  const size_t abase = (size_t)(m0 + sr) * 1024 + q0 * 8;
  const size_t bbase = (size_t)(n0 + sr2) * 1024 + qb * 8;
  for (int k0 = 0; k0 < 1024; k0 += 32) {
    __syncthreads();
    {
      *(bf16x8*)&Ah[wb0] = *(const bf16x8*)(z1h + abase + k0);
      *(bf16x8*)&Ah[wb1] = *(const bf16x8*)(z1h + abase + k0 + 8);
      *(bf16x8*)&Al[wb0] = *(const bf16x8*)(z1l + abase + k0);
      *(bf16x8*)&Al[wb1] = *(const bf16x8*)(z1l + abase + k0 + 8);
      *(bf16x8*)&Bh[wbB] = *(const bf16x8*)(fwh + bbase + k0);
      *(bf16x8*)&Bl[wbB] = *(const bf16x8*)(fwl + bbase + k0);
    }
    __syncthreads();
    bf16x8 ah[4], al[4];
#pragma unroll
    for (int tm = 0; tm < 4; ++tm) {
      ah[tm] = *(const bf16x8*)&Ah[FRAG_IDX(wm * 4 + tm, quad, l15)];
      al[tm] = *(const bf16x8*)&Al[FRAG_IDX(wm * 4 + tm, quad, l15)];
    }
#pragma unroll
    for (int tn = 0; tn < 2; ++tn) {
      const int bi = FRAG_IDX(wn * 2 + tn, quad, l15);
      bf16x8 b0 = *(const bf16x8*)&Bh[bi];
      bf16x8 b1 = *(const bf16x8*)&Bl[bi];
#pragma unroll
      for (int tm = 0; tm < 4; ++tm) {
        f32x4 a = acc[tm][tn];
        a = __builtin_amdgcn_mfma_f32_16x16x32_bf16(ah[tm], b0, a, 0, 0, 0);
        a = __builtin_amdgcn_mfma_f32_16x16x32_bf16(ah[tm], b1, a, 0, 0, 0);
        a = __builtin_amdgcn_mfma_f32_16x16x32_bf16(al[tm], b0, a, 0, 0, 0);
        acc[tm][tn] = a;
      }
    }
  }
  float sum = 0.f, sq = 0.f;
#pragma unroll
  for (int tm = 0; tm < 4; ++tm) {
#pragma unroll
    for (int tn = 0; tn < 2; ++tn) {
#pragma unroll
      for (int r = 0; r < 4; ++r) {
        int m = m0 + wm * 64 + tm * 16 + quad * 4 + r;
        int n = n0 + wn * 32 + tn * 16 + l15;
        size_t idx = (size_t)m * 1024 + n;
        float z1v = bf2f(z1h[idx]) + bf2f(z1l[idx]);
        float o = z1v + fmaxf(acc[tm][tn][r] + ffb[n], 0.f);
        s2[idx] = o;
        sum += o; sq += o * o;
      }
    }
  }
  red[tid] = make_float2(sum, sq);
  __syncthreads();
  for (int s = 128; s > 0; s >>= 1) {
    if (tid < s) { red[tid].x += red[tid + s].x; red[tid].y += red[tid + s].y; }
    __syncthreads();
  }
  // batch = blockIdx.x>>3; 128 partials per batch
  if (tid == 0) part[blockIdx.x * 16 + blockIdx.y] = red[0];
}

__global__ __launch_bounds__(256) void ln_stats(
    const float2* __restrict__ part, float2* __restrict__ stats, int npart)
{
  __shared__ double sd[256], sq[256];
  const int tid = threadIdx.x;
  double as = 0.0, aq = 0.0;
  for (int i = tid; i < npart; i += 256) {
    float2 p = part[blockIdx.x * npart + i];
    as += (double)p.x; aq += (double)p.y;
  }
  sd[tid] = as; sq[tid] = aq;
  __syncthreads();
  for (int s = 128; s > 0; s >>= 1) {
    if (tid < s) { sd[tid] += sd[tid + s]; sq[tid] += sq[tid + s]; }
    __syncthreads();
  }
  if (tid == 0) {
    const double n = (double)Tc * Ec;
    double mean = sd[0] / n;
    double var = sq[0] / n - mean * mean;
    if (var < 0.0) var = 0.0;
    double rs = 1.0 / sqrt(var + 1e-5);
    stats[blockIdx.x] = make_float2((float)mean, (float)rs);
  }
}

// ln_norm -> split2 pair; blocks >= 4096 instead split2 ffw (folded launch).
__global__ __launch_bounds__(256) void ln_norm_split(
    const float* __restrict__ s, const float2* __restrict__ stats,
    const float* __restrict__ w, const float* __restrict__ bias,
    ushort* __restrict__ oh, ushort* __restrict__ ol,
    const float* __restrict__ ffw, ushort* __restrict__ fwh, ushort* __restrict__ fwl)
{
  if (blockIdx.x >= 4096) {
    int i = (blockIdx.x - 4096) * 256 + threadIdx.x;
#pragma unroll
    for (int j = 0; j < 4; ++j) {
      int idx = i * 4 + j;
      float4 v = ((const float4*)ffw)[idx];
      ushort4 h, l;
      split2(v.x, h.x, l.x); split2(v.y, h.y, l.y);
      split2(v.z, h.z, l.z); split2(v.w, h.w, l.w);
      ((ushort4*)fwh)[idx] = h; ((ushort4*)fwl)[idx] = l;
    }
    return;
  }
  int i = blockIdx.x * 256 + threadIdx.x;
  int b = i >> 18;
  int te4 = i & ((1 << 18) - 1);
  float2 st = stats[b];
  float4 sv = ((const float4*)s)[i];
  float4 wv = ((const float4*)w)[te4];
  float4 bv = ((const float4*)bias)[te4];
  float4 o;
  o.x = (sv.x - st.x) * st.y * wv.x + bv.x;
  o.y = (sv.y - st.x) * st.y * wv.y + bv.y;
  o.z = (sv.z - st.x) * st.y * wv.z + bv.z;
  o.w = (sv.w - st.x) * st.y * wv.w + bv.w;
  ushort4 h, l;
  split2(o.x, h.x, l.x); split2(o.y, h.y, l.y);
  split2(o.z, h.z, l.z); split2(o.w, h.w, l.w);
  ((ushort4*)oh)[i] = h; ((ushort4*)ol)[i] = l;
}

__global__ __launch_bounds__(256) void ln_norm(
    const float* __restrict__ s, const float2* __restrict__ stats,
    const float* __restrict__ w, const float* __restrict__ bias,
    float* __restrict__ out)
{
  int i = blockIdx.x * 256 + threadIdx.x;
  if (i >= (Bc * Tc * Ec) / 4) return;
  int b = i >> 18;
  int te4 = i & ((1 << 18) - 1);
  float2 st = stats[b];
  float4 sv = ((const float4*)s)[i];
  float4 wv = ((const float4*)w)[te4];
  float4 bv = ((const float4*)bias)[te4];
  float4 o;
  o.x = (sv.x - st.x) * st.y * wv.x + bv.x;
  o.y = (sv.y - st.x) * st.y * wv.y + bv.y;
  o.z = (sv.z - st.x) * st.y * wv.z + bv.z;
  o.w = (sv.w - st.x) * st.y * wv.w + bv.w;
  ((float4*)out)[i] = o;
}

// ---------------------------------------------------------------------------
extern "C" void kernel_launch(void* const* d_in, const int* in_sizes, int n_in,
                              void* d_out, int out_size, void* d_ws, size_t ws_size,
                              hipStream_t stream)
{
  const float* x    = (const float*)d_in[0];
  const float* qw   = (const float*)d_in[1];
  const float* kw   = (const float*)d_in[2];
  const float* vw   = (const float*)d_in[3];
  const float* frw  = (const float*)d_in[4];
  const float* ffw  = (const float*)d_in[5];
  const float* ffb  = (const float*)d_in[6];
  const float* ln1w = (const float*)d_in[7];
  const float* ln1b = (const float*)d_in[8];
  const float* ln2w = (const float*)d_in[9];
  const float* ln2b = (const float*)d_in[10];
  float* out = (float*)d_out;
  char* W = (char*)d_ws;

  const size_t MB = 1ull << 20;
  // Footprint: 64 MB + 16.4 KB (proven). Same phase liveness as rounds 9/10.
  float*  qf  = (float*)(W);
  ushort* kh  = (ushort*)(W + 16 * MB);
  ushort* km  = (ushort*)(W + 24 * MB);
  ushort* kl  = (ushort*)(W + 32 * MB);
  ushort* vt  = (ushort*)(W + 40 * MB);
  ushort* wT  = (ushort*)(W + 48 * MB);
  ushort* zh  = (ushort*)(W + 48 * MB);
  ushort* zl  = (ushort*)(W + 56 * MB);
  ushort* frT = (ushort*)(W + 16 * MB);
  float*  s1  = (float*)(W);
  ushort* z1h = (ushort*)(W + 16 * MB);
  ushort* z1l = (ushort*)(W + 24 * MB);
  ushort* fwh = (ushort*)(W + 48 * MB);
  ushort* fwl = (ushort*)(W + 50 * MB);
  float*  s2  = (float*)(W + 32 * MB);
  float2* part1  = (float2*)(W + 64 * MB);
  float2* part2  = part1 + 1024;
  float2* stats1 = part2 + 1024;
  float2* stats2 = stats1 + 4;

  transp_w<<<dim3(16, 16, 3), 256, 0, stream>>>(qw, kw, vw, wT);
  proj_all_mfma<<<dim3(32, 8, 3), 256, 0, stream>>>(x, wT, qf, kh, km, kl, vt);
  attn_mfma<<<dim3(8, 64), 512, 0, stream>>>(qf, kh, km, kl, vt, zh, zl);
  transp_frw<<<dim3(16, 16, 4), 256, 0, stream>>>(frw, frT);
  gemm_fr_mfma<<<dim3(8, 16, 4), 256, 0, stream>>>(zh, zl, frT, x, s1, part1);
  ln_stats<<<dim3(4), 256, 0, stream>>>(part1, stats1, 128);
  ln_norm_split<<<dim3(4352), 256, 0, stream>>>(s1, stats1, ln1w, ln1b, z1h, z1l,
                                                ffw, fwh, fwl);
  gemm_ff_mfma<<<dim3(32, 16), 256, 0, stream>>>(z1h, z1l, fwh, fwl, ffb, s2, part2);
  ln_stats<<<dim3(4), 256, 0, stream>>>(part2, stats2, 128);
  ln_norm<<<dim3(4096), 256, 0, stream>>>(s2, stats2, ln2w, ln2b, out);
}